// Round 1
// baseline (5143.669 us; speedup 1.0000x reference)
//
#include <hip/hip_runtime.h>
#include <hip/hip_bf16.h>

#define IN_DIM 32
#define DIMS   32
#define NW     8
#define NB     8
#define TT     16
#define HH     112
#define WW     112
#define HW     (HH*WW)           // 12544
#define CHW    (TT*HW)           // 200704
#define EPS    1e-5f

// ---------------- workspace layout (floats) ----------------
// phi:        [0, 64)
// dyn_w:      [64, 64+221184)
// dyn_b:      [221248, 221504)
// stats:      [221504, 221568)   (sum[32], sumsq[32])
// scaleshift: [221568, 221632)   (scale[32], shift[32])
#define WS_PHI    0
#define WS_DYNW   64
#define WS_DYNB   221248
#define WS_STATS  221504
#define WS_SS     221568

// ---------------- kernel 1: routing CNN -> phi ----------------
__global__ __launch_bounds__(256)
void routing_kernel(const float* __restrict__ std_x, const int* __restrict__ epochs,
                    const float* __restrict__ c1w, const float* __restrict__ c1b,
                    const float* __restrict__ c2w, const float* __restrict__ c2b,
                    const float* __restrict__ fcw, const float* __restrict__ fcb,
                    float* __restrict__ phi_out)
{
    const int b = blockIdx.x;
    const int tid = threadIdx.x;
    __shared__ float sx[32 * 32];
    __shared__ float h1[16 * 28 * 28];
    __shared__ float cmax[32];

    for (int i = tid; i < 1024; i += 256) sx[i] = std_x[b * 1024 + i];
    if (tid < 32) cmax[tid] = 0.f;
    __syncthreads();

    // conv1 5x5 VALID, 1->16 ch, relu
    for (int idx = tid; idx < 16 * 28 * 28; idx += 256) {
        int xw = idx % 28;
        int r = idx / 28;
        int xh = r % 28;
        int oc = r / 28;
        float s = c1b[oc];
        #pragma unroll
        for (int ky = 0; ky < 5; ++ky)
            #pragma unroll
            for (int kx = 0; kx < 5; ++kx)
                s = fmaf(sx[(xh + ky) * 32 + xw + kx], c1w[oc * 25 + ky * 5 + kx], s);
        h1[idx] = fmaxf(s, 0.f);
    }
    __syncthreads();

    // conv2 5x5 VALID, 16->32 ch, relu, max over spatial
    for (int idx = tid; idx < 32 * 24 * 24; idx += 256) {
        int xw = idx % 24;
        int r = idx / 24;
        int xh = r % 24;
        int oc = r / 24;
        float s = c2b[oc];
        for (int ic = 0; ic < 16; ++ic) {
            const float* hp = &h1[ic * 784];
            const float* wp = &c2w[(oc * 16 + ic) * 25];
            #pragma unroll
            for (int ky = 0; ky < 5; ++ky)
                #pragma unroll
                for (int kx = 0; kx < 5; ++kx)
                    s = fmaf(hp[(xh + ky) * 28 + xw + kx], wp[ky * 5 + kx], s);
        }
        s = fmaxf(s, 0.f);
        atomicMax(reinterpret_cast<int*>(&cmax[oc]), __float_as_int(s)); // s>=0: int order == float order
    }
    __syncthreads();

    if (tid == 0) {
        int ep = epochs[0];
        float tau = (ep < 10) ? (30.0f - 2.9f * (float)ep) : 1.0f;
        float lg[8];
        float mx = -1e30f;
        #pragma unroll
        for (int n = 0; n < 8; ++n) {
            float s = fcb[n];
            #pragma unroll
            for (int k = 0; k < 32; ++k) s = fmaf(cmax[k], fcw[n * 32 + k], s);
            lg[n] = s / tau;
            mx = fmaxf(mx, lg[n]);
        }
        float den = 0.f;
        #pragma unroll
        for (int n = 0; n < 8; ++n) { lg[n] = expf(lg[n] - mx); den += lg[n]; }
        #pragma unroll
        for (int n = 0; n < 8; ++n) phi_out[b * 8 + n] = lg[n] / den;
    }
}

// ---------------- kernel 2: dynamic weights/bias + zero stats ----------------
__global__ __launch_bounds__(256)
void dynw_kernel(const float* __restrict__ phi, const float* __restrict__ weights,
                 const float* __restrict__ biases, float* __restrict__ dyn_w,
                 float* __restrict__ dyn_b, float* __restrict__ stats)
{
    const int b = blockIdx.x;
    const int tid = threadIdx.x;
    __shared__ float ph[8];
    if (tid < 8) ph[tid] = phi[b * 8 + tid];
    __syncthreads();

    for (int j = tid; j < DIMS * IN_DIM * 27; j += 256) {
        float s = 0.f;
        #pragma unroll
        for (int n = 0; n < 8; ++n) s = fmaf(ph[n], weights[n * (DIMS * IN_DIM * 27) + j], s);
        dyn_w[b * (DIMS * IN_DIM * 27) + j] = s;
    }
    if (tid < 32) {
        float s = 0.f;
        #pragma unroll
        for (int n = 0; n < 8; ++n) s = fmaf(ph[n], biases[n * 32 + tid], s);
        dyn_b[b * 32 + tid] = s;
    }
    if (b == 0 && tid < 64) stats[tid] = 0.f;
}

// ---------------- kernel 3: dynamic 3x3x3 conv + bias + BN-stat accumulation ----------------
__global__ __launch_bounds__(256)
void conv3d_kernel(const float* __restrict__ x, const float* __restrict__ dyn_w,
                   const float* __restrict__ dyn_b, float* __restrict__ y,
                   float* __restrict__ stats)
{
    const int htile = blockIdx.x;   // 0..55 (2 rows each)
    const int t     = blockIdx.y;   // 0..15
    const int b     = blockIdx.z;   // 0..7
    const int tid   = threadIdx.x;
    const int w     = tid & 127;    // 0..127 (>=112 idle for compute)
    const int hh    = tid >> 7;     // 0..1
    const int h0    = htile * 2;

    __shared__ float tile[3][8][4][114];   // [dt][ic][h(4 rows)][w(-1..112)] 43776 B

    float acc[32];
    #pragma unroll
    for (int c = 0; c < 32; ++c) acc[c] = 0.f;

    const float* wb = dyn_w + b * (DIMS * IN_DIM * 27);
    const float* xb = x + (size_t)b * IN_DIM * CHW;

    for (int ic0 = 0; ic0 < 32; ic0 += 8) {
        __syncthreads();
        // load 3t x 8ic x 4h x 114w tile (zero-padded)
        for (int idx = tid; idx < 3 * 8 * 4 * 114; idx += 256) {
            int w_ = idx % 114;
            int r  = idx / 114;
            int h_ = r & 3;
            int r2 = r >> 2;
            int i_ = r2 & 7;
            int dt_ = r2 >> 3;
            int gt = t + dt_ - 1;
            int gh = h0 - 1 + h_;
            int gw = w_ - 1;
            float v = 0.f;
            if ((unsigned)gt < (unsigned)TT && (unsigned)gh < (unsigned)HH && (unsigned)gw < (unsigned)WW)
                v = xb[(size_t)((ic0 + i_) * TT + gt) * HW + gh * WW + gw];
            tile[dt_][i_][h_][w_] = v;
        }
        __syncthreads();

        if (w < WW) {
            for (int i = 0; i < 8; ++i) {
                #pragma unroll
                for (int dt = 0; dt < 3; ++dt) {
                    float xv[9];
                    #pragma unroll
                    for (int dh = 0; dh < 3; ++dh)
                        #pragma unroll
                        for (int dw = 0; dw < 3; ++dw)
                            xv[dh * 3 + dw] = tile[dt][i][hh + dh][w + dw];
                    const float* wp = wb + (ic0 + i) * 27 + dt * 9;
                    #pragma unroll
                    for (int c = 0; c < 32; ++c) {
                        const float* wc = wp + c * 864;
                        #pragma unroll
                        for (int k = 0; k < 9; ++k)
                            acc[c] = fmaf(xv[k], wc[k], acc[c]);
                    }
                }
            }
        }
    }

    // bias (only active pixels contribute)
    const float* db = dyn_b + b * 32;
    if (w < WW) {
        #pragma unroll
        for (int c = 0; c < 32; ++c) acc[c] += db[c];
    }

    // per-channel sum / sumsq reduction (idle lanes hold 0)
    __shared__ float ssum[32], ssq[32];
    if (tid < 32) { ssum[tid] = 0.f; ssq[tid] = 0.f; }
    __syncthreads();
    #pragma unroll
    for (int c = 0; c < 32; ++c) {
        float s = (w < WW) ? acc[c] : 0.f;
        float q = s * s;
        #pragma unroll
        for (int off = 32; off >= 1; off >>= 1) {
            s += __shfl_down(s, off);
            q += __shfl_down(q, off);
        }
        if ((tid & 63) == 0) { atomicAdd(&ssum[c], s); atomicAdd(&ssq[c], q); }
    }
    __syncthreads();
    if (tid < 32) {
        atomicAdd(&stats[tid], ssum[tid]);
        atomicAdd(&stats[32 + tid], ssq[tid]);
    }

    // store raw y (pre-norm) into d_out
    if (w < WW) {
        size_t base = ((size_t)(b * 32) * TT + t) * HW + (size_t)(h0 + hh) * WW + w;
        #pragma unroll
        for (int c = 0; c < 32; ++c)
            y[base + (size_t)c * CHW] = acc[c];
    }
}

// ---------------- kernel 4: finalize BN stats ----------------
__global__ void stats_finalize_kernel(const float* __restrict__ stats,
                                      const float* __restrict__ gamma,
                                      const float* __restrict__ beta,
                                      float* __restrict__ scaleshift)
{
    int c = threadIdx.x;  // 32 threads
    const float M = (float)NB * (float)CHW;   // 8*200704
    float mean = stats[c] / M;
    float var  = stats[32 + c] / M - mean * mean;
    float sc = gamma[c] * rsqrtf(var + EPS);
    scaleshift[c] = sc;
    scaleshift[32 + c] = beta[c] - mean * sc;
}

// ---------------- kernel 5: in-place normalize + relu ----------------
__global__ __launch_bounds__(256)
void norm_relu_kernel(float* __restrict__ y, const float* __restrict__ scaleshift)
{
    const long long total4 = (long long)NB * DIMS * CHW / 4;  // 12845056
    const int nthreads = gridDim.x * blockDim.x;
    float4* y4 = reinterpret_cast<float4*>(y);
    for (long long i = (long long)blockIdx.x * blockDim.x + threadIdx.x; i < total4; i += nthreads) {
        int c = (int)((i / (CHW / 4)) & 31);
        float sc = scaleshift[c];
        float sh = scaleshift[32 + c];
        float4 v = y4[i];
        v.x = fmaxf(fmaf(v.x, sc, sh), 0.f);
        v.y = fmaxf(fmaf(v.y, sc, sh), 0.f);
        v.z = fmaxf(fmaf(v.z, sc, sh), 0.f);
        v.w = fmaxf(fmaf(v.w, sc, sh), 0.f);
        y4[i] = v;
    }
}

extern "C" void kernel_launch(void* const* d_in, const int* in_sizes, int n_in,
                              void* d_out, int out_size, void* d_ws, size_t ws_size,
                              hipStream_t stream)
{
    const float* x      = (const float*)d_in[0];
    const float* std_x  = (const float*)d_in[1];
    const int*   epochs = (const int*)d_in[2];
    const float* weights= (const float*)d_in[3];
    const float* biases = (const float*)d_in[4];
    const float* c1w    = (const float*)d_in[5];
    const float* c1b    = (const float*)d_in[6];
    const float* c2w    = (const float*)d_in[7];
    const float* c2b    = (const float*)d_in[8];
    const float* fcw    = (const float*)d_in[9];
    const float* fcb    = (const float*)d_in[10];
    const float* gamma  = (const float*)d_in[11];
    const float* beta   = (const float*)d_in[12];

    float* out = (float*)d_out;
    float* ws  = (float*)d_ws;

    float* phi   = ws + WS_PHI;
    float* dyn_w = ws + WS_DYNW;
    float* dyn_b = ws + WS_DYNB;
    float* stats = ws + WS_STATS;
    float* ss    = ws + WS_SS;

    routing_kernel<<<NB, 256, 0, stream>>>(std_x, epochs, c1w, c1b, c2w, c2b, fcw, fcb, phi);
    dynw_kernel<<<NB, 256, 0, stream>>>(phi, weights, biases, dyn_w, dyn_b, stats);
    conv3d_kernel<<<dim3(HH / 2, TT, NB), 256, 0, stream>>>(x, dyn_w, dyn_b, out, stats);
    stats_finalize_kernel<<<1, 32, 0, stream>>>(stats, gamma, beta, ss);
    norm_relu_kernel<<<2048, 256, 0, stream>>>(out, ss);
}

// Round 2
// 982.596 us; speedup vs baseline: 5.2348x; 5.2348x over previous
//
#include <hip/hip_runtime.h>
#include <hip/hip_bf16.h>

#define IN_DIM 32
#define DIMS   32
#define NW     8
#define NB     8
#define TT     16
#define HH     112
#define WW     112
#define HW     (HH*WW)           // 12544
#define CHW    (TT*HW)           // 200704
#define EPS    1e-5f

typedef __attribute__((ext_vector_type(8))) short bf16x8;
typedef __attribute__((ext_vector_type(4))) float f32x4;

static __device__ __forceinline__ unsigned short f2bf(float f) {
    unsigned u = __float_as_uint(f);
    unsigned r = u + 0x7FFFu + ((u >> 16) & 1u);
    return (unsigned short)(r >> 16);
}

// ======================= fast-path ws layout =======================
// floats:   phi[64] | dyn_b[256] | stats[64] | ss[64]   (448 floats = 1792 B)
// then:     dwb  bf16 [8][27][32oc][32ic]  = 221184 ushorts (442368 B)
// then:     xT   bf16 [8][16][112][112][32] = 51380224 ushorts (102760448 B)
#define WSF_PHI    0
#define WSF_DYNB   64
#define WSF_STATS  320
#define WSF_SS     384
#define WSF_HDR_FLOATS 448
#define DWB_USHORTS (NW*27*1024)          // note: per-b 27*1024; total 8*27*1024
#define XT_USHORTS  ((size_t)NB*CHW*32)
#define WS_NEED_BYTES (WSF_HDR_FLOATS*4 + (size_t)NB*27*1024*2 + XT_USHORTS*2)

// ======================= fallback ws layout (round-1) ==============
#define WS_PHI    0
#define WS_DYNW   64
#define WS_DYNB   221248
#define WS_STATS  221504
#define WS_SS     221568

// ---------------- kernel 1: routing CNN -> phi (shared) ----------------
__global__ __launch_bounds__(256)
void routing_kernel(const float* __restrict__ std_x, const int* __restrict__ epochs,
                    const float* __restrict__ c1w, const float* __restrict__ c1b,
                    const float* __restrict__ c2w, const float* __restrict__ c2b,
                    const float* __restrict__ fcw, const float* __restrict__ fcb,
                    float* __restrict__ phi_out)
{
    const int b = blockIdx.x;
    const int tid = threadIdx.x;
    __shared__ float sx[32 * 32];
    __shared__ float h1[16 * 28 * 28];
    __shared__ float cmax[32];

    for (int i = tid; i < 1024; i += 256) sx[i] = std_x[b * 1024 + i];
    if (tid < 32) cmax[tid] = 0.f;
    __syncthreads();

    for (int idx = tid; idx < 16 * 28 * 28; idx += 256) {
        int xw = idx % 28;
        int r = idx / 28;
        int xh = r % 28;
        int oc = r / 28;
        float s = c1b[oc];
        #pragma unroll
        for (int ky = 0; ky < 5; ++ky)
            #pragma unroll
            for (int kx = 0; kx < 5; ++kx)
                s = fmaf(sx[(xh + ky) * 32 + xw + kx], c1w[oc * 25 + ky * 5 + kx], s);
        h1[idx] = fmaxf(s, 0.f);
    }
    __syncthreads();

    for (int idx = tid; idx < 32 * 24 * 24; idx += 256) {
        int xw = idx % 24;
        int r = idx / 24;
        int xh = r % 24;
        int oc = r / 24;
        float s = c2b[oc];
        for (int ic = 0; ic < 16; ++ic) {
            const float* hp = &h1[ic * 784];
            const float* wp = &c2w[(oc * 16 + ic) * 25];
            #pragma unroll
            for (int ky = 0; ky < 5; ++ky)
                #pragma unroll
                for (int kx = 0; kx < 5; ++kx)
                    s = fmaf(hp[(xh + ky) * 28 + xw + kx], wp[ky * 5 + kx], s);
        }
        s = fmaxf(s, 0.f);
        atomicMax(reinterpret_cast<int*>(&cmax[oc]), __float_as_int(s));
    }
    __syncthreads();

    if (tid == 0) {
        int ep = epochs[0];
        float tau = (ep < 10) ? (30.0f - 2.9f * (float)ep) : 1.0f;
        float lg[8];
        float mx = -1e30f;
        #pragma unroll
        for (int n = 0; n < 8; ++n) {
            float s = fcb[n];
            #pragma unroll
            for (int k = 0; k < 32; ++k) s = fmaf(cmax[k], fcw[n * 32 + k], s);
            lg[n] = s / tau;
            mx = fmaxf(mx, lg[n]);
        }
        float den = 0.f;
        #pragma unroll
        for (int n = 0; n < 8; ++n) { lg[n] = expf(lg[n] - mx); den += lg[n]; }
        #pragma unroll
        for (int n = 0; n < 8; ++n) phi_out[b * 8 + n] = lg[n] / den;
    }
}

// ---------------- fast kernel A: x (NCDHW f32) -> xT (NDHWC bf16) ----------------
#define XS 232   // LDS row stride bytes per ic
__global__ __launch_bounds__(256)
void xpose_kernel(const float* __restrict__ x, unsigned short* __restrict__ xT)
{
    const int h = blockIdx.x, t = blockIdx.y, b = blockIdx.z;
    const int tid = threadIdx.x;
    __shared__ __align__(16) unsigned char lds[32 * XS];

    for (int idx = tid; idx < 32 * 112; idx += 256) {
        int ic = idx / 112;
        int w = idx - ic * 112;
        float v = x[(((size_t)(b * 32 + ic) * TT + t) * HW) + h * 112 + w];
        *(unsigned short*)(lds + ic * XS + w * 2) = f2bf(v);
    }
    __syncthreads();

    unsigned short* op = xT + ((((size_t)b * TT + t) * HH + h) * WW) * 32;
    for (int idx = tid; idx < 448; idx += 256) {   // 112 w * 4 icg
        int w = idx >> 2, icg = idx & 3;
        unsigned int pk[4];
        #pragma unroll
        for (int j = 0; j < 4; ++j) {
            unsigned short lo = *(unsigned short*)(lds + (icg * 8 + 2 * j) * XS + w * 2);
            unsigned short hi = *(unsigned short*)(lds + (icg * 8 + 2 * j + 1) * XS + w * 2);
            pk[j] = (unsigned int)lo | ((unsigned int)hi << 16);
        }
        uint4 v; v.x = pk[0]; v.y = pk[1]; v.z = pk[2]; v.w = pk[3];
        *(uint4*)(op + (size_t)w * 32 + icg * 8) = v;
    }
}

// ---------------- fast kernel B: dyn weights -> bf16 [b][tap][oc][ic], dyn_b, zero stats ----
__global__ __launch_bounds__(256)
void dynwb_kernel(const float* __restrict__ phi, const float* __restrict__ weights,
                  const float* __restrict__ biases, unsigned short* __restrict__ dwb,
                  float* __restrict__ dyn_b, float* __restrict__ stats)
{
    const int tap = blockIdx.x;   // 0..26
    const int b   = blockIdx.y;   // 0..7
    const int tid = threadIdx.x;
    __shared__ float ph[8];
    if (tid < 8) ph[tid] = phi[b * 8 + tid];
    __syncthreads();

    for (int e = tid; e < 1024; e += 256) {
        int oc = e >> 5, ic = e & 31;
        float s = 0.f;
        #pragma unroll
        for (int n = 0; n < 8; ++n)
            s = fmaf(ph[n], weights[(((size_t)n * 32 + oc) * 32 + ic) * 27 + tap], s);
        dwb[((size_t)(b * 27 + tap) << 10) + e] = f2bf(s);
    }
    if (tap == 0) {
        if (tid < 32) {
            float s = 0.f;
            #pragma unroll
            for (int n = 0; n < 8; ++n) s = fmaf(ph[n], biases[n * 32 + tid], s);
            dyn_b[b * 32 + tid] = s;
        }
        if (b == 0 && tid >= 64 && tid < 128) stats[tid - 64] = 0.f;
    }
}

// ---------------- fast kernel C: MFMA conv3d + bias + BN stats ----------------
// block: 256 thr (4 waves) -> (b, tpair, 16h x 16w), all 32 oc, 2 t outputs
#define ROWSTRIDE (18 * 64)          // bytes: 18 px * 32ic*2B
#define PLANE_BYTES (18 * ROWSTRIDE) // 20736
__global__ __launch_bounds__(256, 3)
void convmf_kernel(const unsigned short* __restrict__ xT, const unsigned short* __restrict__ dwb,
                   const float* __restrict__ dyn_b, float* __restrict__ y,
                   float* __restrict__ stats)
{
    const int hblk = blockIdx.x / 7, wblk = blockIdx.x % 7;
    const int tpair = blockIdx.y, b = blockIdx.z;
    const int h0 = hblk * 16, w0 = wblk * 16, t0 = tpair * 2;
    const int tid = threadIdx.x;
    const int lane = tid & 63, wv = tid >> 6;
    const int l15 = lane & 15, lg = lane >> 4;

    __shared__ __align__(16) unsigned char ldsx[2 * PLANE_BYTES];
    __shared__ float sred[64];

    f32x4 acc0[4][2], acc1[4][2];
    #pragma unroll
    for (int g = 0; g < 4; ++g)
        #pragma unroll
        for (int M = 0; M < 2; ++M) { acc0[g][M] = (f32x4)0.f; acc1[g][M] = (f32x4)0.f; }

    const unsigned short* wbase = dwb + (size_t)b * 27 * 1024;

    for (int tp = 0; tp < 4; ++tp) {
        // ---- stage x-plane t = t0-1+tp into slot tp&1 ----
        {
            const int tx = t0 - 1 + tp;
            unsigned char* ldsp = ldsx + (tp & 1) * PLANE_BYTES;
            const bool tok = (unsigned)tx < (unsigned)TT;
            for (int cid = tid; cid < 1296; cid += 256) {  // 18*18*4
                int hr = cid / 72;
                int rem = cid - hr * 72;
                int p = rem >> 2, icg = rem & 3;
                int gh = h0 - 1 + hr, gw = w0 - 1 + p;
                uint4 v; v.x = 0; v.y = 0; v.z = 0; v.w = 0;
                if (tok && (unsigned)gh < (unsigned)HH && (unsigned)gw < (unsigned)WW)
                    v = *(const uint4*)(xT + ((((size_t)b * TT + tx) * HH + gh) * WW + gw) * 32 + icg * 8);
                *(uint4*)(ldsp + hr * ROWSTRIDE + p * 64 + icg * 16) = v;
            }
        }
        __syncthreads();

        const bool do0 = (tp <= 2), do1 = (tp >= 1);
        const int dt0 = tp, dt1 = tp - 1;
        const unsigned char* ldsp = ldsx + (tp & 1) * PLANE_BYTES;

        #pragma unroll
        for (int dhw = 0; dhw < 9; ++dhw) {
            const int dh = dhw / 3, dw = dhw - dh * 3;
            bf16x8 a00, a01, a10, a11;
            if (do0) {
                const unsigned short* wp = wbase + (dt0 * 9 + dhw) * 1024 + l15 * 32 + lg * 8;
                a00 = *(const bf16x8*)(wp);
                a01 = *(const bf16x8*)(wp + 512);
            }
            if (do1) {
                const unsigned short* wp = wbase + (dt1 * 9 + dhw) * 1024 + l15 * 32 + lg * 8;
                a10 = *(const bf16x8*)(wp);
                a11 = *(const bf16x8*)(wp + 512);
            }
            const unsigned char* bb0 = ldsp + (wv * 4 + dh) * ROWSTRIDE + (l15 + dw) * 64 + lg * 16;
            #pragma unroll
            for (int g = 0; g < 4; ++g) {
                bf16x8 bb = *(const bf16x8*)(bb0 + g * ROWSTRIDE);
                if (do0) {
                    acc0[g][0] = __builtin_amdgcn_mfma_f32_16x16x32_bf16(a00, bb, acc0[g][0], 0, 0, 0);
                    acc0[g][1] = __builtin_amdgcn_mfma_f32_16x16x32_bf16(a01, bb, acc0[g][1], 0, 0, 0);
                }
                if (do1) {
                    acc1[g][0] = __builtin_amdgcn_mfma_f32_16x16x32_bf16(a10, bb, acc1[g][0], 0, 0, 0);
                    acc1[g][1] = __builtin_amdgcn_mfma_f32_16x16x32_bf16(a11, bb, acc1[g][1], 0, 0, 0);
                }
            }
        }
        __syncthreads();
    }

    // ---- epilogue: bias, stats, store ----
    f32x4 bias[2];
    #pragma unroll
    for (int M = 0; M < 2; ++M)
        #pragma unroll
        for (int r = 0; r < 4; ++r)
            bias[M][r] = dyn_b[b * 32 + 16 * M + lg * 4 + r];

    float sumv[2][4], sqv[2][4];
    #pragma unroll
    for (int M = 0; M < 2; ++M)
        #pragma unroll
        for (int r = 0; r < 4; ++r) { sumv[M][r] = 0.f; sqv[M][r] = 0.f; }

    #pragma unroll
    for (int g = 0; g < 4; ++g) {
        const int h = h0 + wv * 4 + g;
        #pragma unroll
        for (int M = 0; M < 2; ++M) {
            f32x4 v0 = acc0[g][M] + bias[M];
            f32x4 v1 = acc1[g][M] + bias[M];
            const int oc0 = 16 * M + lg * 4;
            size_t base = (((size_t)(b * 32 + oc0) * TT + t0) * HW) + h * 112 + w0 + l15;
            #pragma unroll
            for (int r = 0; r < 4; ++r) {
                sumv[M][r] += v0[r] + v1[r];
                sqv[M][r]  += v0[r] * v0[r] + v1[r] * v1[r];
                y[base + (size_t)r * TT * HW] = v0[r];
                y[base + (size_t)r * TT * HW + HW] = v1[r];
            }
        }
    }

    #pragma unroll
    for (int off = 1; off < 16; off <<= 1) {
        #pragma unroll
        for (int M = 0; M < 2; ++M)
            #pragma unroll
            for (int r = 0; r < 4; ++r) {
                sumv[M][r] += __shfl_xor(sumv[M][r], off);
                sqv[M][r]  += __shfl_xor(sqv[M][r], off);
            }
    }
    if (tid < 64) sred[tid] = 0.f;
    __syncthreads();
    if (l15 == 0) {
        #pragma unroll
        for (int M = 0; M < 2; ++M)
            #pragma unroll
            for (int r = 0; r < 4; ++r) {
                int ch = 16 * M + lg * 4 + r;
                atomicAdd(&sred[ch], sumv[M][r]);
                atomicAdd(&sred[32 + ch], sqv[M][r]);
            }
    }
    __syncthreads();
    if (tid < 64) atomicAdd(&stats[tid], sred[tid]);
}

// ---------------- fallback kernels (round-1 fp32 path) ----------------
__global__ __launch_bounds__(256)
void dynw_kernel(const float* __restrict__ phi, const float* __restrict__ weights,
                 const float* __restrict__ biases, float* __restrict__ dyn_w,
                 float* __restrict__ dyn_b, float* __restrict__ stats)
{
    const int b = blockIdx.x;
    const int tid = threadIdx.x;
    __shared__ float ph[8];
    if (tid < 8) ph[tid] = phi[b * 8 + tid];
    __syncthreads();

    for (int j = tid; j < DIMS * IN_DIM * 27; j += 256) {
        float s = 0.f;
        #pragma unroll
        for (int n = 0; n < 8; ++n) s = fmaf(ph[n], weights[n * (DIMS * IN_DIM * 27) + j], s);
        dyn_w[b * (DIMS * IN_DIM * 27) + j] = s;
    }
    if (tid < 32) {
        float s = 0.f;
        #pragma unroll
        for (int n = 0; n < 8; ++n) s = fmaf(ph[n], biases[n * 32 + tid], s);
        dyn_b[b * 32 + tid] = s;
    }
    if (b == 0 && tid < 64) stats[tid] = 0.f;
}

__global__ __launch_bounds__(256)
void conv3d_kernel(const float* __restrict__ x, const float* __restrict__ dyn_w,
                   const float* __restrict__ dyn_b, float* __restrict__ y,
                   float* __restrict__ stats)
{
    const int htile = blockIdx.x;
    const int t     = blockIdx.y;
    const int b     = blockIdx.z;
    const int tid   = threadIdx.x;
    const int w     = tid & 127;
    const int hh    = tid >> 7;
    const int h0    = htile * 2;

    __shared__ float tile[3][8][4][114];

    float acc[32];
    #pragma unroll
    for (int c = 0; c < 32; ++c) acc[c] = 0.f;

    const float* wb = dyn_w + b * (DIMS * IN_DIM * 27);
    const float* xb = x + (size_t)b * IN_DIM * CHW;

    for (int ic0 = 0; ic0 < 32; ic0 += 8) {
        __syncthreads();
        for (int idx = tid; idx < 3 * 8 * 4 * 114; idx += 256) {
            int w_ = idx % 114;
            int r  = idx / 114;
            int h_ = r & 3;
            int r2 = r >> 2;
            int i_ = r2 & 7;
            int dt_ = r2 >> 3;
            int gt = t + dt_ - 1;
            int gh = h0 - 1 + h_;
            int gw = w_ - 1;
            float v = 0.f;
            if ((unsigned)gt < (unsigned)TT && (unsigned)gh < (unsigned)HH && (unsigned)gw < (unsigned)WW)
                v = xb[(size_t)((ic0 + i_) * TT + gt) * HW + gh * WW + gw];
            tile[dt_][i_][h_][w_] = v;
        }
        __syncthreads();

        if (w < WW) {
            for (int i = 0; i < 8; ++i) {
                #pragma unroll
                for (int dt = 0; dt < 3; ++dt) {
                    float xv[9];
                    #pragma unroll
                    for (int dh = 0; dh < 3; ++dh)
                        #pragma unroll
                        for (int dw = 0; dw < 3; ++dw)
                            xv[dh * 3 + dw] = tile[dt][i][hh + dh][w + dw];
                    const float* wp = wb + (ic0 + i) * 27 + dt * 9;
                    #pragma unroll
                    for (int c = 0; c < 32; ++c) {
                        const float* wc = wp + c * 864;
                        #pragma unroll
                        for (int k = 0; k < 9; ++k)
                            acc[c] = fmaf(xv[k], wc[k], acc[c]);
                    }
                }
            }
        }
    }

    const float* db = dyn_b + b * 32;
    if (w < WW) {
        #pragma unroll
        for (int c = 0; c < 32; ++c) acc[c] += db[c];
    }

    __shared__ float ssum[32], ssq[32];
    if (tid < 32) { ssum[tid] = 0.f; ssq[tid] = 0.f; }
    __syncthreads();
    #pragma unroll
    for (int c = 0; c < 32; ++c) {
        float s = (w < WW) ? acc[c] : 0.f;
        float q = s * s;
        #pragma unroll
        for (int off = 32; off >= 1; off >>= 1) {
            s += __shfl_down(s, off);
            q += __shfl_down(q, off);
        }
        if ((tid & 63) == 0) { atomicAdd(&ssum[c], s); atomicAdd(&ssq[c], q); }
    }
    __syncthreads();
    if (tid < 32) {
        atomicAdd(&stats[tid], ssum[tid]);
        atomicAdd(&stats[32 + tid], ssq[tid]);
    }

    if (w < WW) {
        size_t base = ((size_t)(b * 32) * TT + t) * HW + (size_t)(h0 + hh) * WW + w;
        #pragma unroll
        for (int c = 0; c < 32; ++c)
            y[base + (size_t)c * CHW] = acc[c];
    }
}

// ---------------- shared: finalize + norm ----------------
__global__ void stats_finalize_kernel(const float* __restrict__ stats,
                                      const float* __restrict__ gamma,
                                      const float* __restrict__ beta,
                                      float* __restrict__ scaleshift)
{
    int c = threadIdx.x;
    const float M = (float)NB * (float)CHW;
    float mean = stats[c] / M;
    float var  = stats[32 + c] / M - mean * mean;
    float sc = gamma[c] * rsqrtf(var + EPS);
    scaleshift[c] = sc;
    scaleshift[32 + c] = beta[c] - mean * sc;
}

__global__ __launch_bounds__(256)
void norm_relu_kernel(float* __restrict__ y, const float* __restrict__ scaleshift)
{
    const long long total4 = (long long)NB * DIMS * CHW / 4;
    const int nthreads = gridDim.x * blockDim.x;
    float4* y4 = reinterpret_cast<float4*>(y);
    for (long long i = (long long)blockIdx.x * blockDim.x + threadIdx.x; i < total4; i += nthreads) {
        int c = (int)((i / (CHW / 4)) & 31);
        float sc = scaleshift[c];
        float sh = scaleshift[32 + c];
        float4 v = y4[i];
        v.x = fmaxf(fmaf(v.x, sc, sh), 0.f);
        v.y = fmaxf(fmaf(v.y, sc, sh), 0.f);
        v.z = fmaxf(fmaf(v.z, sc, sh), 0.f);
        v.w = fmaxf(fmaf(v.w, sc, sh), 0.f);
        y4[i] = v;
    }
}

extern "C" void kernel_launch(void* const* d_in, const int* in_sizes, int n_in,
                              void* d_out, int out_size, void* d_ws, size_t ws_size,
                              hipStream_t stream)
{
    const float* x      = (const float*)d_in[0];
    const float* std_x  = (const float*)d_in[1];
    const int*   epochs = (const int*)d_in[2];
    const float* weights= (const float*)d_in[3];
    const float* biases = (const float*)d_in[4];
    const float* c1w    = (const float*)d_in[5];
    const float* c1b    = (const float*)d_in[6];
    const float* c2w    = (const float*)d_in[7];
    const float* c2b    = (const float*)d_in[8];
    const float* fcw    = (const float*)d_in[9];
    const float* fcb    = (const float*)d_in[10];
    const float* gamma  = (const float*)d_in[11];
    const float* beta   = (const float*)d_in[12];

    float* out = (float*)d_out;
    float* ws  = (float*)d_ws;

    if (ws_size >= WS_NEED_BYTES) {
        // ---------------- fast bf16-MFMA path ----------------
        float* phi   = ws + WSF_PHI;
        float* dyn_b = ws + WSF_DYNB;
        float* stats = ws + WSF_STATS;
        float* ss    = ws + WSF_SS;
        unsigned short* dwb = (unsigned short*)(ws + WSF_HDR_FLOATS);
        unsigned short* xT  = dwb + (size_t)NB * 27 * 1024;

        routing_kernel<<<NB, 256, 0, stream>>>(std_x, epochs, c1w, c1b, c2w, c2b, fcw, fcb, phi);
        dynwb_kernel<<<dim3(27, NB), 256, 0, stream>>>(phi, weights, biases, dwb, dyn_b, stats);
        xpose_kernel<<<dim3(HH, TT, NB), 256, 0, stream>>>(x, xT);
        convmf_kernel<<<dim3(49, 8, NB), 256, 0, stream>>>(xT, dwb, dyn_b, out, stats);
        stats_finalize_kernel<<<1, 32, 0, stream>>>(stats, gamma, beta, ss);
        norm_relu_kernel<<<2048, 256, 0, stream>>>(out, ss);
    } else {
        // ---------------- fallback fp32 path ----------------
        float* phi   = ws + WS_PHI;
        float* dyn_w = ws + WS_DYNW;
        float* dyn_b = ws + WS_DYNB;
        float* stats = ws + WS_STATS;
        float* ss    = ws + WS_SS;

        routing_kernel<<<NB, 256, 0, stream>>>(std_x, epochs, c1w, c1b, c2w, c2b, fcw, fcb, phi);
        dynw_kernel<<<NB, 256, 0, stream>>>(phi, weights, biases, dyn_w, dyn_b, stats);
        conv3d_kernel<<<dim3(HH / 2, TT, NB), 256, 0, stream>>>(x, dyn_w, dyn_b, out, stats);
        stats_finalize_kernel<<<1, 32, 0, stream>>>(stats, gamma, beta, ss);
        norm_relu_kernel<<<2048, 256, 0, stream>>>(out, ss);
    }
}

// Round 3
// 682.019 us; speedup vs baseline: 7.5418x; 1.4407x over previous
//
#include <hip/hip_runtime.h>
#include <hip/hip_bf16.h>

#define IN_DIM 32
#define DIMS   32
#define NW     8
#define NB     8
#define TT     16
#define HH     112
#define WW     112
#define HW     (HH*WW)           // 12544
#define CHW    (TT*HW)           // 200704
#define EPS    1e-5f

typedef __attribute__((ext_vector_type(8))) short bf16x8;
typedef __attribute__((ext_vector_type(4))) float f32x4;

static __device__ __forceinline__ unsigned short f2bf(float f) {
    unsigned u = __float_as_uint(f);
    unsigned r = u + 0x7FFFu + ((u >> 16) & 1u);
    return (unsigned short)(r >> 16);
}

// ======================= fast-path ws layout (IDENTICAL footprint to round 2) ==========
// floats:   phi[64] | dyn_b[256] | stats[64] | (64 unused)   (448 floats)
// then:     dwb  bf16 [8][27][32oc][32ic]  = 221184 ushorts
// then:     xT   bf16 [8][16][112][112][32] = 51380224 ushorts
// routing scratch (h1: 8*16*28*28 floats, cmax: 8*32 floats) is ALIASED into the
// xT region — it is fully consumed before xpose_kernel overwrites xT (stream-serial).
#define WSF_PHI    0
#define WSF_DYNB   64
#define WSF_STATS  320
#define WSF_HDR_FLOATS 448
#define XT_USHORTS  ((size_t)NB*CHW*32)
#define WS_NEED_BYTES (WSF_HDR_FLOATS*4 + (size_t)NB*27*1024*2 + XT_USHORTS*2)

// ======================= fallback ws layout (round-1) ==============
#define WS_PHI    0
#define WS_DYNW   64
#define WS_DYNB   221248
#define WS_STATS  221504
#define WS_SS     221568

// ---------------- fast routing 1: conv1 5x5 VALID 1->16 + relu ----------------
// grid (16 oc, 8 b), 256 thr
__global__ __launch_bounds__(256)
void routing_conv1_kernel(const float* __restrict__ std_x,
                          const float* __restrict__ c1w, const float* __restrict__ c1b,
                          float* __restrict__ h1g)
{
    const int oc = blockIdx.x, b = blockIdx.y;
    const int tid = threadIdx.x;
    __shared__ float sx[1024];
    for (int i = tid; i < 1024; i += 256) sx[i] = std_x[b * 1024 + i];
    __syncthreads();

    float wloc[25];
    #pragma unroll
    for (int k = 0; k < 25; ++k) wloc[k] = c1w[oc * 25 + k];
    const float bias = c1b[oc];

    for (int idx = tid; idx < 784; idx += 256) {
        int xw = idx % 28, xh = idx / 28;
        float s = bias;
        #pragma unroll
        for (int ky = 0; ky < 5; ++ky)
            #pragma unroll
            for (int kx = 0; kx < 5; ++kx)
                s = fmaf(sx[(xh + ky) * 32 + xw + kx], wloc[ky * 5 + kx], s);
        h1g[(b * 16 + oc) * 784 + idx] = fmaxf(s, 0.f);
    }
}

// ---------------- fast routing 2: conv2 5x5 VALID 16->32 + relu + spatial max ----
// grid (32 oc, 8 b), 256 thr; writes cmax[b*32+oc] (no atomics)
__global__ __launch_bounds__(256)
void routing_conv2max_kernel(const float* __restrict__ h1g,
                             const float* __restrict__ c2w, const float* __restrict__ c2b,
                             float* __restrict__ cmax)
{
    const int oc = blockIdx.x, b = blockIdx.y;
    const int tid = threadIdx.x;
    __shared__ float h1s[16 * 784];   // 50176 B
    __shared__ float wred[4];

    for (int i = tid; i < 16 * 784; i += 256) h1s[i] = h1g[b * (16 * 784) + i];
    __syncthreads();

    float m = 0.f;
    for (int idx = tid; idx < 576; idx += 256) {
        int xw = idx % 24, xh = idx / 24;
        float s = c2b[oc];
        for (int ic = 0; ic < 16; ++ic) {
            const float* hp = &h1s[ic * 784];
            const float* wp = &c2w[(oc * 16 + ic) * 25];
            #pragma unroll
            for (int ky = 0; ky < 5; ++ky)
                #pragma unroll
                for (int kx = 0; kx < 5; ++kx)
                    s = fmaf(hp[(xh + ky) * 28 + xw + kx], wp[ky * 5 + kx], s);
        }
        m = fmaxf(m, s);   // relu(max) == max vs 0
    }
    #pragma unroll
    for (int off = 32; off >= 1; off >>= 1) m = fmaxf(m, __shfl_down(m, off));
    if ((tid & 63) == 0) wred[tid >> 6] = m;
    __syncthreads();
    if (tid == 0) {
        float r = fmaxf(fmaxf(wred[0], wred[1]), fmaxf(wred[2], wred[3]));
        cmax[b * 32 + oc] = r;
    }
}

// ---------------- fast routing 3: fc + softmax -> phi ----------------
// 1 block, 64 thr: thread = b*8+n
__global__ __launch_bounds__(64)
void routing_fc_kernel(const float* __restrict__ cmax, const int* __restrict__ epochs,
                       const float* __restrict__ fcw, const float* __restrict__ fcb,
                       float* __restrict__ phi_out)
{
    const int tid = threadIdx.x;
    const int b = tid >> 3, n = tid & 7;
    int ep = epochs[0];
    float tau = (ep < 10) ? (30.0f - 2.9f * (float)ep) : 1.0f;
    float s = fcb[n];
    #pragma unroll
    for (int k = 0; k < 32; ++k) s = fmaf(cmax[b * 32 + k], fcw[n * 32 + k], s);
    s /= tau;
    float mx = s;
    #pragma unroll
    for (int off = 1; off < 8; off <<= 1) mx = fmaxf(mx, __shfl_xor(mx, off, 8));
    float e = expf(s - mx);
    float den = e;
    #pragma unroll
    for (int off = 1; off < 8; off <<= 1) den += __shfl_xor(den, off, 8);
    phi_out[b * 8 + n] = e / den;
}

// ---------------- fast kernel A: x (NCDHW f32) -> xT (NDHWC bf16) ----------------
#define XS 232   // LDS row stride bytes per ic
__global__ __launch_bounds__(256)
void xpose_kernel(const float* __restrict__ x, unsigned short* __restrict__ xT)
{
    const int h = blockIdx.x, t = blockIdx.y, b = blockIdx.z;
    const int tid = threadIdx.x;
    __shared__ __align__(16) unsigned char lds[32 * XS];

    for (int idx = tid; idx < 32 * 112; idx += 256) {
        int ic = idx / 112;
        int w = idx - ic * 112;
        float v = x[(((size_t)(b * 32 + ic) * TT + t) * HW) + h * 112 + w];
        *(unsigned short*)(lds + ic * XS + w * 2) = f2bf(v);
    }
    __syncthreads();

    unsigned short* op = xT + ((((size_t)b * TT + t) * HH + h) * WW) * 32;
    for (int idx = tid; idx < 448; idx += 256) {   // 112 w * 4 icg
        int w = idx >> 2, icg = idx & 3;
        unsigned int pk[4];
        #pragma unroll
        for (int j = 0; j < 4; ++j) {
            unsigned short lo = *(unsigned short*)(lds + (icg * 8 + 2 * j) * XS + w * 2);
            unsigned short hi = *(unsigned short*)(lds + (icg * 8 + 2 * j + 1) * XS + w * 2);
            pk[j] = (unsigned int)lo | ((unsigned int)hi << 16);
        }
        uint4 v; v.x = pk[0]; v.y = pk[1]; v.z = pk[2]; v.w = pk[3];
        *(uint4*)(op + (size_t)w * 32 + icg * 8) = v;
    }
}

// ---------------- fast kernel B: dyn weights -> bf16 [b][tap][oc][ic], dyn_b, zero stats ----
__global__ __launch_bounds__(256)
void dynwb_kernel(const float* __restrict__ phi, const float* __restrict__ weights,
                  const float* __restrict__ biases, unsigned short* __restrict__ dwb,
                  float* __restrict__ dyn_b, float* __restrict__ stats)
{
    const int tap = blockIdx.x;   // 0..26
    const int b   = blockIdx.y;   // 0..7
    const int tid = threadIdx.x;
    __shared__ float ph[8];
    if (tid < 8) ph[tid] = phi[b * 8 + tid];
    __syncthreads();

    for (int e = tid; e < 1024; e += 256) {
        int oc = e >> 5, ic = e & 31;
        float s = 0.f;
        #pragma unroll
        for (int n = 0; n < 8; ++n)
            s = fmaf(ph[n], weights[(((size_t)n * 32 + oc) * 32 + ic) * 27 + tap], s);
        dwb[((size_t)(b * 27 + tap) << 10) + e] = f2bf(s);
    }
    if (tap == 0) {
        if (tid < 32) {
            float s = 0.f;
            #pragma unroll
            for (int n = 0; n < 8; ++n) s = fmaf(ph[n], biases[n * 32 + tid], s);
            dyn_b[b * 32 + tid] = s;
        }
        if (b == 0 && tid >= 64 && tid < 128) stats[tid - 64] = 0.f;
    }
}

// ---------------- fast kernel C: MFMA conv3d + bias + BN stats ----------------
// block: 256 thr (4 waves) -> (b, tpair, 16h x 16w), all 32 oc, 2 t outputs
#define ROWSTRIDE (18 * 64)          // bytes: 18 px * 32ic*2B
#define PLANE_BYTES (18 * ROWSTRIDE) // 20736
__global__ __launch_bounds__(256, 3)
void convmf_kernel(const unsigned short* __restrict__ xT, const unsigned short* __restrict__ dwb,
                   const float* __restrict__ dyn_b, float* __restrict__ y,
                   float* __restrict__ stats)
{
    const int hblk = blockIdx.x / 7, wblk = blockIdx.x % 7;
    const int tpair = blockIdx.y, b = blockIdx.z;
    const int h0 = hblk * 16, w0 = wblk * 16, t0 = tpair * 2;
    const int tid = threadIdx.x;
    const int lane = tid & 63, wv = tid >> 6;
    const int l15 = lane & 15, lg = lane >> 4;

    __shared__ __align__(16) unsigned char ldsx[2 * PLANE_BYTES];
    __shared__ float sred[64];

    f32x4 acc0[4][2], acc1[4][2];
    #pragma unroll
    for (int g = 0; g < 4; ++g)
        #pragma unroll
        for (int M = 0; M < 2; ++M) { acc0[g][M] = (f32x4)0.f; acc1[g][M] = (f32x4)0.f; }

    const unsigned short* wbase = dwb + (size_t)b * 27 * 1024;

    for (int tp = 0; tp < 4; ++tp) {
        {
            const int tx = t0 - 1 + tp;
            unsigned char* ldsp = ldsx + (tp & 1) * PLANE_BYTES;
            const bool tok = (unsigned)tx < (unsigned)TT;
            for (int cid = tid; cid < 1296; cid += 256) {  // 18*18*4
                int hr = cid / 72;
                int rem = cid - hr * 72;
                int p = rem >> 2, icg = rem & 3;
                int gh = h0 - 1 + hr, gw = w0 - 1 + p;
                uint4 v; v.x = 0; v.y = 0; v.z = 0; v.w = 0;
                if (tok && (unsigned)gh < (unsigned)HH && (unsigned)gw < (unsigned)WW)
                    v = *(const uint4*)(xT + ((((size_t)b * TT + tx) * HH + gh) * WW + gw) * 32 + icg * 8);
                *(uint4*)(ldsp + hr * ROWSTRIDE + p * 64 + icg * 16) = v;
            }
        }
        __syncthreads();

        const bool do0 = (tp <= 2), do1 = (tp >= 1);
        const int dt0 = tp, dt1 = tp - 1;
        const unsigned char* ldsp = ldsx + (tp & 1) * PLANE_BYTES;

        #pragma unroll
        for (int dhw = 0; dhw < 9; ++dhw) {
            const int dh = dhw / 3, dw = dhw - dh * 3;
            bf16x8 a00, a01, a10, a11;
            if (do0) {
                const unsigned short* wp = wbase + (dt0 * 9 + dhw) * 1024 + l15 * 32 + lg * 8;
                a00 = *(const bf16x8*)(wp);
                a01 = *(const bf16x8*)(wp + 512);
            }
            if (do1) {
                const unsigned short* wp = wbase + (dt1 * 9 + dhw) * 1024 + l15 * 32 + lg * 8;
                a10 = *(const bf16x8*)(wp);
                a11 = *(const bf16x8*)(wp + 512);
            }
            const unsigned char* bb0 = ldsp + (wv * 4 + dh) * ROWSTRIDE + (l15 + dw) * 64 + lg * 16;
            #pragma unroll
            for (int g = 0; g < 4; ++g) {
                bf16x8 bb = *(const bf16x8*)(bb0 + g * ROWSTRIDE);
                if (do0) {
                    acc0[g][0] = __builtin_amdgcn_mfma_f32_16x16x32_bf16(a00, bb, acc0[g][0], 0, 0, 0);
                    acc0[g][1] = __builtin_amdgcn_mfma_f32_16x16x32_bf16(a01, bb, acc0[g][1], 0, 0, 0);
                }
                if (do1) {
                    acc1[g][0] = __builtin_amdgcn_mfma_f32_16x16x32_bf16(a10, bb, acc1[g][0], 0, 0, 0);
                    acc1[g][1] = __builtin_amdgcn_mfma_f32_16x16x32_bf16(a11, bb, acc1[g][1], 0, 0, 0);
                }
            }
        }
        __syncthreads();
    }

    // ---- epilogue: bias, stats, store ----
    f32x4 bias[2];
    #pragma unroll
    for (int M = 0; M < 2; ++M)
        #pragma unroll
        for (int r = 0; r < 4; ++r)
            bias[M][r] = dyn_b[b * 32 + 16 * M + lg * 4 + r];

    float sumv[2][4], sqv[2][4];
    #pragma unroll
    for (int M = 0; M < 2; ++M)
        #pragma unroll
        for (int r = 0; r < 4; ++r) { sumv[M][r] = 0.f; sqv[M][r] = 0.f; }

    #pragma unroll
    for (int g = 0; g < 4; ++g) {
        const int h = h0 + wv * 4 + g;
        #pragma unroll
        for (int M = 0; M < 2; ++M) {
            f32x4 v0 = acc0[g][M] + bias[M];
            f32x4 v1 = acc1[g][M] + bias[M];
            const int oc0 = 16 * M + lg * 4;
            size_t base = (((size_t)(b * 32 + oc0) * TT + t0) * HW) + h * 112 + w0 + l15;
            #pragma unroll
            for (int r = 0; r < 4; ++r) {
                sumv[M][r] += v0[r] + v1[r];
                sqv[M][r]  += v0[r] * v0[r] + v1[r] * v1[r];
                y[base + (size_t)r * TT * HW] = v0[r];
                y[base + (size_t)r * TT * HW + HW] = v1[r];
            }
        }
    }

    #pragma unroll
    for (int off = 1; off < 16; off <<= 1) {
        #pragma unroll
        for (int M = 0; M < 2; ++M)
            #pragma unroll
            for (int r = 0; r < 4; ++r) {
                sumv[M][r] += __shfl_xor(sumv[M][r], off);
                sqv[M][r]  += __shfl_xor(sqv[M][r], off);
            }
    }
    if (tid < 64) sred[tid] = 0.f;
    __syncthreads();
    if (l15 == 0) {
        #pragma unroll
        for (int M = 0; M < 2; ++M)
            #pragma unroll
            for (int r = 0; r < 4; ++r) {
                int ch = 16 * M + lg * 4 + r;
                atomicAdd(&sred[ch], sumv[M][r]);
                atomicAdd(&sred[32 + ch], sqv[M][r]);
            }
    }
    __syncthreads();
    if (tid < 64) atomicAdd(&stats[tid], sred[tid]);
}

// ---------------- fast kernel D: fused finalize + normalize + relu ----------------
__global__ __launch_bounds__(256)
void norm_relu_fused_kernel(float* __restrict__ y, const float* __restrict__ stats,
                            const float* __restrict__ gamma, const float* __restrict__ beta)
{
    __shared__ float ssc[32], ssh[32];
    if (threadIdx.x < 32) {
        int c = threadIdx.x;
        const float M = (float)NB * (float)CHW;
        float mean = stats[c] / M;
        float var  = stats[32 + c] / M - mean * mean;
        float sc = gamma[c] * rsqrtf(var + EPS);
        ssc[c] = sc;
        ssh[c] = beta[c] - mean * sc;
    }
    __syncthreads();

    const long long total4 = (long long)NB * DIMS * CHW / 4;
    const int nthreads = gridDim.x * blockDim.x;
    float4* y4 = reinterpret_cast<float4*>(y);
    for (long long i = (long long)blockIdx.x * blockDim.x + threadIdx.x; i < total4; i += nthreads) {
        int c = (int)((i / (CHW / 4)) & 31);
        float sc = ssc[c];
        float sh = ssh[c];
        float4 v = y4[i];
        v.x = fmaxf(fmaf(v.x, sc, sh), 0.f);
        v.y = fmaxf(fmaf(v.y, sc, sh), 0.f);
        v.z = fmaxf(fmaf(v.z, sc, sh), 0.f);
        v.w = fmaxf(fmaf(v.w, sc, sh), 0.f);
        y4[i] = v;
    }
}

// ================= fallback kernels (round-1 fp32 path) =================
__global__ __launch_bounds__(256)
void routing_kernel(const float* __restrict__ std_x, const int* __restrict__ epochs,
                    const float* __restrict__ c1w, const float* __restrict__ c1b,
                    const float* __restrict__ c2w, const float* __restrict__ c2b,
                    const float* __restrict__ fcw, const float* __restrict__ fcb,
                    float* __restrict__ phi_out)
{
    const int b = blockIdx.x;
    const int tid = threadIdx.x;
    __shared__ float sx[32 * 32];
    __shared__ float h1[16 * 28 * 28];
    __shared__ float cmax[32];

    for (int i = tid; i < 1024; i += 256) sx[i] = std_x[b * 1024 + i];
    if (tid < 32) cmax[tid] = 0.f;
    __syncthreads();

    for (int idx = tid; idx < 16 * 28 * 28; idx += 256) {
        int xw = idx % 28;
        int r = idx / 28;
        int xh = r % 28;
        int oc = r / 28;
        float s = c1b[oc];
        #pragma unroll
        for (int ky = 0; ky < 5; ++ky)
            #pragma unroll
            for (int kx = 0; kx < 5; ++kx)
                s = fmaf(sx[(xh + ky) * 32 + xw + kx], c1w[oc * 25 + ky * 5 + kx], s);
        h1[idx] = fmaxf(s, 0.f);
    }
    __syncthreads();

    for (int idx = tid; idx < 32 * 24 * 24; idx += 256) {
        int xw = idx % 24;
        int r = idx / 24;
        int xh = r % 24;
        int oc = r / 24;
        float s = c2b[oc];
        for (int ic = 0; ic < 16; ++ic) {
            const float* hp = &h1[ic * 784];
            const float* wp = &c2w[(oc * 16 + ic) * 25];
            #pragma unroll
            for (int ky = 0; ky < 5; ++ky)
                #pragma unroll
                for (int kx = 0; kx < 5; ++kx)
                    s = fmaf(hp[(xh + ky) * 28 + xw + kx], wp[ky * 5 + kx], s);
        }
        s = fmaxf(s, 0.f);
        atomicMax(reinterpret_cast<int*>(&cmax[oc]), __float_as_int(s));
    }
    __syncthreads();

    if (tid == 0) {
        int ep = epochs[0];
        float tau = (ep < 10) ? (30.0f - 2.9f * (float)ep) : 1.0f;
        float lg[8];
        float mx = -1e30f;
        #pragma unroll
        for (int n = 0; n < 8; ++n) {
            float s = fcb[n];
            #pragma unroll
            for (int k = 0; k < 32; ++k) s = fmaf(cmax[k], fcw[n * 32 + k], s);
            lg[n] = s / tau;
            mx = fmaxf(mx, lg[n]);
        }
        float den = 0.f;
        #pragma unroll
        for (int n = 0; n < 8; ++n) { lg[n] = expf(lg[n] - mx); den += lg[n]; }
        #pragma unroll
        for (int n = 0; n < 8; ++n) phi_out[b * 8 + n] = lg[n] / den;
    }
}

__global__ __launch_bounds__(256)
void dynw_kernel(const float* __restrict__ phi, const float* __restrict__ weights,
                 const float* __restrict__ biases, float* __restrict__ dyn_w,
                 float* __restrict__ dyn_b, float* __restrict__ stats)
{
    const int b = blockIdx.x;
    const int tid = threadIdx.x;
    __shared__ float ph[8];
    if (tid < 8) ph[tid] = phi[b * 8 + tid];
    __syncthreads();

    for (int j = tid; j < DIMS * IN_DIM * 27; j += 256) {
        float s = 0.f;
        #pragma unroll
        for (int n = 0; n < 8; ++n) s = fmaf(ph[n], weights[n * (DIMS * IN_DIM * 27) + j], s);
        dyn_w[b * (DIMS * IN_DIM * 27) + j] = s;
    }
    if (tid < 32) {
        float s = 0.f;
        #pragma unroll
        for (int n = 0; n < 8; ++n) s = fmaf(ph[n], biases[n * 32 + tid], s);
        dyn_b[b * 32 + tid] = s;
    }
    if (b == 0 && tid < 64) stats[tid] = 0.f;
}

__global__ __launch_bounds__(256)
void conv3d_kernel(const float* __restrict__ x, const float* __restrict__ dyn_w,
                   const float* __restrict__ dyn_b, float* __restrict__ y,
                   float* __restrict__ stats)
{
    const int htile = blockIdx.x;
    const int t     = blockIdx.y;
    const int b     = blockIdx.z;
    const int tid   = threadIdx.x;
    const int w     = tid & 127;
    const int hh    = tid >> 7;
    const int h0    = htile * 2;

    __shared__ float tile[3][8][4][114];

    float acc[32];
    #pragma unroll
    for (int c = 0; c < 32; ++c) acc[c] = 0.f;

    const float* wb = dyn_w + b * (DIMS * IN_DIM * 27);
    const float* xb = x + (size_t)b * IN_DIM * CHW;

    for (int ic0 = 0; ic0 < 32; ic0 += 8) {
        __syncthreads();
        for (int idx = tid; idx < 3 * 8 * 4 * 114; idx += 256) {
            int w_ = idx % 114;
            int r  = idx / 114;
            int h_ = r & 3;
            int r2 = r >> 2;
            int i_ = r2 & 7;
            int dt_ = r2 >> 3;
            int gt = t + dt_ - 1;
            int gh = h0 - 1 + h_;
            int gw = w_ - 1;
            float v = 0.f;
            if ((unsigned)gt < (unsigned)TT && (unsigned)gh < (unsigned)HH && (unsigned)gw < (unsigned)WW)
                v = xb[(size_t)((ic0 + i_) * TT + gt) * HW + gh * WW + gw];
            tile[dt_][i_][h_][w_] = v;
        }
        __syncthreads();

        if (w < WW) {
            for (int i = 0; i < 8; ++i) {
                #pragma unroll
                for (int dt = 0; dt < 3; ++dt) {
                    float xv[9];
                    #pragma unroll
                    for (int dh = 0; dh < 3; ++dh)
                        #pragma unroll
                        for (int dw = 0; dw < 3; ++dw)
                            xv[dh * 3 + dw] = tile[dt][i][hh + dh][w + dw];
                    const float* wp = wb + (ic0 + i) * 27 + dt * 9;
                    #pragma unroll
                    for (int c = 0; c < 32; ++c) {
                        const float* wc = wp + c * 864;
                        #pragma unroll
                        for (int k = 0; k < 9; ++k)
                            acc[c] = fmaf(xv[k], wc[k], acc[c]);
                    }
                }
            }
        }
    }

    const float* db = dyn_b + b * 32;
    if (w < WW) {
        #pragma unroll
        for (int c = 0; c < 32; ++c) acc[c] += db[c];
    }

    __shared__ float ssum[32], ssq[32];
    if (tid < 32) { ssum[tid] = 0.f; ssq[tid] = 0.f; }
    __syncthreads();
    #pragma unroll
    for (int c = 0; c < 32; ++c) {
        float s = (w < WW) ? acc[c] : 0.f;
        float q = s * s;
        #pragma unroll
        for (int off = 32; off >= 1; off >>= 1) {
            s += __shfl_down(s, off);
            q += __shfl_down(q, off);
        }
        if ((tid & 63) == 0) { atomicAdd(&ssum[c], s); atomicAdd(&ssq[c], q); }
    }
    __syncthreads();
    if (tid < 32) {
        atomicAdd(&stats[tid], ssum[tid]);
        atomicAdd(&stats[32 + tid], ssq[tid]);
    }

    if (w < WW) {
        size_t base = ((size_t)(b * 32) * TT + t) * HW + (size_t)(h0 + hh) * WW + w;
        #pragma unroll
        for (int c = 0; c < 32; ++c)
            y[base + (size_t)c * CHW] = acc[c];
    }
}

__global__ void stats_finalize_kernel(const float* __restrict__ stats,
                                      const float* __restrict__ gamma,
                                      const float* __restrict__ beta,
                                      float* __restrict__ scaleshift)
{
    int c = threadIdx.x;
    const float M = (float)NB * (float)CHW;
    float mean = stats[c] / M;
    float var  = stats[32 + c] / M - mean * mean;
    float sc = gamma[c] * rsqrtf(var + EPS);
    scaleshift[c] = sc;
    scaleshift[32 + c] = beta[c] - mean * sc;
}

__global__ __launch_bounds__(256)
void norm_relu_kernel(float* __restrict__ y, const float* __restrict__ scaleshift)
{
    const long long total4 = (long long)NB * DIMS * CHW / 4;
    const int nthreads = gridDim.x * blockDim.x;
    float4* y4 = reinterpret_cast<float4*>(y);
    for (long long i = (long long)blockIdx.x * blockDim.x + threadIdx.x; i < total4; i += nthreads) {
        int c = (int)((i / (CHW / 4)) & 31);
        float sc = scaleshift[c];
        float sh = scaleshift[32 + c];
        float4 v = y4[i];
        v.x = fmaxf(fmaf(v.x, sc, sh), 0.f);
        v.y = fmaxf(fmaf(v.y, sc, sh), 0.f);
        v.z = fmaxf(fmaf(v.z, sc, sh), 0.f);
        v.w = fmaxf(fmaf(v.w, sc, sh), 0.f);
        y4[i] = v;
    }
}

extern "C" void kernel_launch(void* const* d_in, const int* in_sizes, int n_in,
                              void* d_out, int out_size, void* d_ws, size_t ws_size,
                              hipStream_t stream)
{
    const float* x      = (const float*)d_in[0];
    const float* std_x  = (const float*)d_in[1];
    const int*   epochs = (const int*)d_in[2];
    const float* weights= (const float*)d_in[3];
    const float* biases = (const float*)d_in[4];
    const float* c1w    = (const float*)d_in[5];
    const float* c1b    = (const float*)d_in[6];
    const float* c2w    = (const float*)d_in[7];
    const float* c2b    = (const float*)d_in[8];
    const float* fcw    = (const float*)d_in[9];
    const float* fcb    = (const float*)d_in[10];
    const float* gamma  = (const float*)d_in[11];
    const float* beta   = (const float*)d_in[12];

    float* out = (float*)d_out;
    float* ws  = (float*)d_ws;

    if (ws_size >= WS_NEED_BYTES) {
        // ---------------- fast bf16-MFMA path ----------------
        float* phi   = ws + WSF_PHI;
        float* dyn_b = ws + WSF_DYNB;
        float* stats = ws + WSF_STATS;
        unsigned short* dwb = (unsigned short*)(ws + WSF_HDR_FLOATS);
        unsigned short* xT  = dwb + (size_t)NB * 27 * 1024;
        // routing scratch aliased into xT region (consumed before xpose overwrites)
        float* h1g  = (float*)xT;
        float* cmax = h1g + NB * 16 * 784;

        routing_conv1_kernel<<<dim3(16, NB), 256, 0, stream>>>(std_x, c1w, c1b, h1g);
        routing_conv2max_kernel<<<dim3(32, NB), 256, 0, stream>>>(h1g, c2w, c2b, cmax);
        routing_fc_kernel<<<1, 64, 0, stream>>>(cmax, epochs, fcw, fcb, phi);
        dynwb_kernel<<<dim3(27, NB), 256, 0, stream>>>(phi, weights, biases, dwb, dyn_b, stats);
        xpose_kernel<<<dim3(HH, TT, NB), 256, 0, stream>>>(x, xT);
        convmf_kernel<<<dim3(49, 8, NB), 256, 0, stream>>>(xT, dwb, dyn_b, out, stats);
        norm_relu_fused_kernel<<<2048, 256, 0, stream>>>(out, stats, gamma, beta);
    } else {
        // ---------------- fallback fp32 path ----------------
        float* phi   = ws + WS_PHI;
        float* dyn_w = ws + WS_DYNW;
        float* dyn_b = ws + WS_DYNB;
        float* stats = ws + WS_STATS;
        float* ss    = ws + WS_SS;

        routing_kernel<<<NB, 256, 0, stream>>>(std_x, epochs, c1w, c1b, c2w, c2b, fcw, fcb, phi);
        dynw_kernel<<<NB, 256, 0, stream>>>(phi, weights, biases, dyn_w, dyn_b, stats);
        conv3d_kernel<<<dim3(HH / 2, TT, NB), 256, 0, stream>>>(x, dyn_w, dyn_b, out, stats);
        stats_finalize_kernel<<<1, 32, 0, stream>>>(stats, gamma, beta, ss);
        norm_relu_kernel<<<2048, 256, 0, stream>>>(out, ss);
    }
}

// Round 4
// 634.108 us; speedup vs baseline: 8.1117x; 1.0756x over previous
//
#include <hip/hip_runtime.h>
#include <hip/hip_bf16.h>

#define IN_DIM 32
#define DIMS   32
#define NW     8
#define NB     8
#define TT     16
#define HH     112
#define WW     112
#define HW     (HH*WW)           // 12544
#define CHW    (TT*HW)           // 200704
#define EPS    1e-5f

typedef __attribute__((ext_vector_type(8))) short bf16x8;
typedef __attribute__((ext_vector_type(4))) float f32x4;

static __device__ __forceinline__ unsigned short f2bf(float f) {
    unsigned u = __float_as_uint(f);
    unsigned r = u + 0x7FFFu + ((u >> 16) & 1u);
    return (unsigned short)(r >> 16);
}

static __device__ __forceinline__ void gload_lds16(const void* gptr, void* lptr) {
    __builtin_amdgcn_global_load_lds(
        (const __attribute__((address_space(1))) unsigned int*)gptr,
        (__attribute__((address_space(3))) unsigned int*)lptr,
        16, 0, 0);
}

// ======================= fast-path ws layout (IDENTICAL footprint to round 2/3) =======
// floats:   phi[64] | dyn_b[256] | stats[64] | zerobuf[64]   (448 floats)
// then:     dwb  bf16 [8][27][32oc][32ic]  = 221184 ushorts
// then:     xT   bf16 [8][16][112][112][32] = 51380224 ushorts
#define WSF_PHI    0
#define WSF_DYNB   64
#define WSF_STATS  320
#define WSF_ZERO   384
#define WSF_HDR_FLOATS 448
#define XT_USHORTS  ((size_t)NB*CHW*32)
#define WS_NEED_BYTES (WSF_HDR_FLOATS*4 + (size_t)NB*27*1024*2 + XT_USHORTS*2)

// ======================= fallback ws layout (round-1) ==============
#define WS_PHI    0
#define WS_DYNW   64
#define WS_DYNB   221248
#define WS_STATS  221504
#define WS_SS     221568

// ---------------- fast routing 1: conv1 5x5 VALID 1->16 + relu ----------------
__global__ __launch_bounds__(256)
void routing_conv1_kernel(const float* __restrict__ std_x,
                          const float* __restrict__ c1w, const float* __restrict__ c1b,
                          float* __restrict__ h1g)
{
    const int oc = blockIdx.x, b = blockIdx.y;
    const int tid = threadIdx.x;
    __shared__ float sx[1024];
    for (int i = tid; i < 1024; i += 256) sx[i] = std_x[b * 1024 + i];
    __syncthreads();

    float wloc[25];
    #pragma unroll
    for (int k = 0; k < 25; ++k) wloc[k] = c1w[oc * 25 + k];
    const float bias = c1b[oc];

    for (int idx = tid; idx < 784; idx += 256) {
        int xw = idx % 28, xh = idx / 28;
        float s = bias;
        #pragma unroll
        for (int ky = 0; ky < 5; ++ky)
            #pragma unroll
            for (int kx = 0; kx < 5; ++kx)
                s = fmaf(sx[(xh + ky) * 32 + xw + kx], wloc[ky * 5 + kx], s);
        h1g[(b * 16 + oc) * 784 + idx] = fmaxf(s, 0.f);
    }
}

// ---------------- fast routing 2: conv2 5x5 VALID 16->32 + relu + spatial max ----
__global__ __launch_bounds__(256)
void routing_conv2max_kernel(const float* __restrict__ h1g,
                             const float* __restrict__ c2w, const float* __restrict__ c2b,
                             float* __restrict__ cmax)
{
    const int oc = blockIdx.x, b = blockIdx.y;
    const int tid = threadIdx.x;
    __shared__ float h1s[16 * 784];   // 50176 B
    __shared__ float wred[4];

    for (int i = tid; i < 16 * 784; i += 256) h1s[i] = h1g[b * (16 * 784) + i];
    __syncthreads();

    float m = 0.f;
    for (int idx = tid; idx < 576; idx += 256) {
        int xw = idx % 24, xh = idx / 24;
        float s = c2b[oc];
        for (int ic = 0; ic < 16; ++ic) {
            const float* hp = &h1s[ic * 784];
            const float* wp = &c2w[(oc * 16 + ic) * 25];
            #pragma unroll
            for (int ky = 0; ky < 5; ++ky)
                #pragma unroll
                for (int kx = 0; kx < 5; ++kx)
                    s = fmaf(hp[(xh + ky) * 28 + xw + kx], wp[ky * 5 + kx], s);
        }
        m = fmaxf(m, s);
    }
    #pragma unroll
    for (int off = 32; off >= 1; off >>= 1) m = fmaxf(m, __shfl_down(m, off));
    if ((tid & 63) == 0) wred[tid >> 6] = m;
    __syncthreads();
    if (tid == 0) {
        float r = fmaxf(fmaxf(wred[0], wred[1]), fmaxf(wred[2], wred[3]));
        cmax[b * 32 + oc] = r;
    }
}

// ---------------- fast routing 3: fc + softmax -> phi ----------------
__global__ __launch_bounds__(64)
void routing_fc_kernel(const float* __restrict__ cmax, const int* __restrict__ epochs,
                       const float* __restrict__ fcw, const float* __restrict__ fcb,
                       float* __restrict__ phi_out)
{
    const int tid = threadIdx.x;
    const int b = tid >> 3, n = tid & 7;
    int ep = epochs[0];
    float tau = (ep < 10) ? (30.0f - 2.9f * (float)ep) : 1.0f;
    float s = fcb[n];
    #pragma unroll
    for (int k = 0; k < 32; ++k) s = fmaf(cmax[b * 32 + k], fcw[n * 32 + k], s);
    s /= tau;
    float mx = s;
    #pragma unroll
    for (int off = 1; off < 8; off <<= 1) mx = fmaxf(mx, __shfl_xor(mx, off, 8));
    float e = expf(s - mx);
    float den = e;
    #pragma unroll
    for (int off = 1; off < 8; off <<= 1) den += __shfl_xor(den, off, 8);
    phi_out[b * 8 + n] = e / den;
}

// ---------------- fast kernel A: x (NCDHW f32) -> xT (NDHWC bf16) ----------------
#define XS 232   // LDS row stride bytes per ic (multiple of 8)
__global__ __launch_bounds__(256)
void xpose_kernel(const float* __restrict__ x, unsigned short* __restrict__ xT)
{
    const int h = blockIdx.x, t = blockIdx.y, b = blockIdx.z;
    const int tid = threadIdx.x;
    __shared__ __align__(16) unsigned char lds[32 * XS];

    for (int idx = tid; idx < 32 * 28; idx += 256) {
        int ic = idx / 28;
        int w4 = idx - ic * 28;
        const float4 v = *(const float4*)(x + (((size_t)(b * 32 + ic) * TT + t) * HW) + h * 112 + w4 * 4);
        uint2 pk;
        pk.x = (unsigned)f2bf(v.x) | ((unsigned)f2bf(v.y) << 16);
        pk.y = (unsigned)f2bf(v.z) | ((unsigned)f2bf(v.w) << 16);
        *(uint2*)(lds + ic * XS + w4 * 8) = pk;
    }
    __syncthreads();

    unsigned short* op = xT + ((((size_t)b * TT + t) * HH + h) * WW) * 32;
    for (int idx = tid; idx < 448; idx += 256) {   // 112 w * 4 icg
        int w = idx >> 2, icg = idx & 3;
        unsigned int pk[4];
        #pragma unroll
        for (int j = 0; j < 4; ++j) {
            unsigned short lo = *(unsigned short*)(lds + (icg * 8 + 2 * j) * XS + w * 2);
            unsigned short hi = *(unsigned short*)(lds + (icg * 8 + 2 * j + 1) * XS + w * 2);
            pk[j] = (unsigned int)lo | ((unsigned int)hi << 16);
        }
        uint4 v; v.x = pk[0]; v.y = pk[1]; v.z = pk[2]; v.w = pk[3];
        *(uint4*)(op + (size_t)w * 32 + icg * 8) = v;
    }
}

// ---------------- fast kernel B: dyn weights (coalesced) -> bf16 [b][tap][oc][ic] ----
// grid (32 oc, 8 b), 256 thr. Also dyn_b, zero stats+zerobuf.
__global__ __launch_bounds__(256)
void dynwb_kernel(const float* __restrict__ phi, const float* __restrict__ weights,
                  const float* __restrict__ biases, unsigned short* __restrict__ dwb,
                  float* __restrict__ dyn_b, float* __restrict__ statszero)
{
    const int oc = blockIdx.x;   // 0..31
    const int b  = blockIdx.y;   // 0..7
    const int tid = threadIdx.x;
    __shared__ float ph[8];
    if (tid < 8) ph[tid] = phi[b * 8 + tid];
    __syncthreads();

    // i indexes (ic*27 + tap) within the contiguous 864-float run for (n, oc)
    for (int i = tid; i < 864; i += 256) {
        float s = 0.f;
        #pragma unroll
        for (int n = 0; n < 8; ++n)
            s = fmaf(ph[n], weights[(size_t)(n * 32 + oc) * 864 + i], s);
        int ic = i / 27;
        int tap = i - 27 * ic;
        dwb[((size_t)(b * 27 + tap) << 10) + (oc << 5) + ic] = f2bf(s);
    }
    if (tid == 0) {
        float s = 0.f;
        #pragma unroll
        for (int n = 0; n < 8; ++n) s = fmaf(ph[n], biases[n * 32 + oc], s);
        dyn_b[b * 32 + oc] = s;
    }
    if (oc == 0 && b == 0 && tid < 128) statszero[tid] = 0.f;  // stats[64] + zerobuf[64]
}

// ---------------- fast kernel C: MFMA conv3d + bias + BN stats (pipelined) ----------
// block: 256 thr (4 waves) -> (b, tpair, 16h x 16w), all 32 oc, 2 t outputs
#define ROWSTRIDE   (18 * 64)            // bytes: 18 px * 32ic*2B
#define CELLS       1296                 // 18*18*4 16B transfers per plane
#define BUF_BYTES   (1536 * 16)          // padded to 6*256 cells = 24576 B
#define PLANE_BYTES_G 802816ull          // t-plane stride in xT (bytes)
__global__ __launch_bounds__(256, 3)
void convmf_kernel(const unsigned short* __restrict__ xT, const unsigned short* __restrict__ dwb,
                   const float* __restrict__ dyn_b, const float* __restrict__ zerobuf,
                   float* __restrict__ y, float* __restrict__ stats)
{
    const int hblk = blockIdx.x / 7, wblk = blockIdx.x % 7;
    const int tpair = blockIdx.y, b = blockIdx.z;
    const int h0 = hblk * 16, w0 = wblk * 16, t0 = tpair * 2;
    const int tid = threadIdx.x;
    const int lane = tid & 63, wv = tid >> 6;
    const int l15 = lane & 15, lg = lane >> 4;

    __shared__ __align__(16) unsigned char ldsx[2 * BUF_BYTES];
    __shared__ float sred[4][64];

    // ---- precompute per-lane staging source columns (6 cells per thread) ----
    const unsigned char* xTbase = (const unsigned char*)xT + (size_t)b * TT * PLANE_BYTES_G;
    const unsigned char* zbp = (const unsigned char*)zerobuf;
    const unsigned char* cb[6];
    bool okhw[6];
    #pragma unroll
    for (int j = 0; j < 6; ++j) {
        int cid = j * 256 + tid;
        int hr = cid / 72, rem = cid - hr * 72;
        int p = rem >> 2, icg = rem & 3;
        int gh = h0 - 1 + hr, gw = w0 - 1 + p;
        okhw[j] = (cid < CELLS) && ((unsigned)gh < (unsigned)HH) && ((unsigned)gw < (unsigned)WW);
        cb[j] = xTbase + (ptrdiff_t)(gh * WW + gw) * 64 + icg * 16;
    }
    unsigned char* lwave = ldsx + (size_t)(tid & ~63) * 16;   // + sel*BUF_BYTES + j*4096

#define STAGE(TX, SEL) do {                                                   \
        const int tx_ = (TX);                                                 \
        const bool tok_ = ((unsigned)tx_ < (unsigned)TT);                     \
        const size_t toff_ = (size_t)tx_ * PLANE_BYTES_G;                     \
        unsigned char* lb_ = lwave + (SEL) * BUF_BYTES;                       \
        _Pragma("unroll")                                                     \
        for (int j = 0; j < 6; ++j) {                                         \
            const unsigned char* s_ = (tok_ && okhw[j]) ? cb[j] + toff_ : zbp;\
            gload_lds16(s_, lb_ + j * 4096);                                  \
        }                                                                     \
    } while (0)

    f32x4 acc0[4][2], acc1[4][2];
    #pragma unroll
    for (int g = 0; g < 4; ++g)
        #pragma unroll
        for (int M = 0; M < 2; ++M) { acc0[g][M] = (f32x4)0.f; acc1[g][M] = (f32x4)0.f; }

    const unsigned short* wbase = dwb + (size_t)b * 27 * 1024;

    // prologue: stage plane 0 (t = t0-1)
    STAGE(t0 - 1, 0);
    asm volatile("s_waitcnt vmcnt(0)" ::: "memory");
    __syncthreads();

    #pragma unroll
    for (int tp = 0; tp < 4; ++tp) {
        const bool do0 = (tp <= 2), do1 = (tp >= 1);
        const int dt0 = tp, dt1 = tp - 1;
        const unsigned char* ldsp = ldsx + (tp & 1) * BUF_BYTES;

        #pragma unroll
        for (int dhw = 0; dhw < 9; ++dhw) {
            const int dh = dhw / 3, dw = dhw - dh * 3;
            bf16x8 a00, a01, a10, a11;
            if (do0) {
                const unsigned short* wp = wbase + (dt0 * 9 + dhw) * 1024 + l15 * 32 + lg * 8;
                a00 = *(const bf16x8*)(wp);
                a01 = *(const bf16x8*)(wp + 512);
            }
            if (do1) {
                const unsigned short* wp = wbase + (dt1 * 9 + dhw) * 1024 + l15 * 32 + lg * 8;
                a10 = *(const bf16x8*)(wp);
                a11 = *(const bf16x8*)(wp + 512);
            }
            const unsigned char* bb0 = ldsp + (wv * 4 + dh) * ROWSTRIDE + (l15 + dw) * 64 + lg * 16;
            #pragma unroll
            for (int g = 0; g < 4; ++g) {
                bf16x8 bb = *(const bf16x8*)(bb0 + g * ROWSTRIDE);
                if (do0) {
                    acc0[g][0] = __builtin_amdgcn_mfma_f32_16x16x32_bf16(a00, bb, acc0[g][0], 0, 0, 0);
                    acc0[g][1] = __builtin_amdgcn_mfma_f32_16x16x32_bf16(a01, bb, acc0[g][1], 0, 0, 0);
                }
                if (do1) {
                    acc1[g][0] = __builtin_amdgcn_mfma_f32_16x16x32_bf16(a10, bb, acc1[g][0], 0, 0, 0);
                    acc1[g][1] = __builtin_amdgcn_mfma_f32_16x16x32_bf16(a11, bb, acc1[g][1], 0, 0, 0);
                }
            }
        }

        // prefetch next plane into the other buffer (issued after this plane's
        // weight loads so in-order vmcnt never stalls weights on staging)
        if (tp < 3) STAGE(t0 + tp, (tp + 1) & 1);

        asm volatile("s_waitcnt vmcnt(0)" ::: "memory");
        __syncthreads();
    }
#undef STAGE

    // ---- epilogue: bias, stats, store ----
    f32x4 bias[2];
    #pragma unroll
    for (int M = 0; M < 2; ++M)
        #pragma unroll
        for (int r = 0; r < 4; ++r)
            bias[M][r] = dyn_b[b * 32 + 16 * M + lg * 4 + r];

    float sumv[2][4], sqv[2][4];
    #pragma unroll
    for (int M = 0; M < 2; ++M)
        #pragma unroll
        for (int r = 0; r < 4; ++r) { sumv[M][r] = 0.f; sqv[M][r] = 0.f; }

    #pragma unroll
    for (int g = 0; g < 4; ++g) {
        const int h = h0 + wv * 4 + g;
        #pragma unroll
        for (int M = 0; M < 2; ++M) {
            f32x4 v0 = acc0[g][M] + bias[M];
            f32x4 v1 = acc1[g][M] + bias[M];
            const int oc0 = 16 * M + lg * 4;
            size_t base = (((size_t)(b * 32 + oc0) * TT + t0) * HW) + h * 112 + w0 + l15;
            #pragma unroll
            for (int r = 0; r < 4; ++r) {
                sumv[M][r] += v0[r] + v1[r];
                sqv[M][r]  += v0[r] * v0[r] + v1[r] * v1[r];
                y[base + (size_t)r * TT * HW] = v0[r];
                y[base + (size_t)r * TT * HW + HW] = v1[r];
            }
        }
    }

    #pragma unroll
    for (int off = 1; off < 16; off <<= 1) {
        #pragma unroll
        for (int M = 0; M < 2; ++M)
            #pragma unroll
            for (int r = 0; r < 4; ++r) {
                sumv[M][r] += __shfl_xor(sumv[M][r], off);
                sqv[M][r]  += __shfl_xor(sqv[M][r], off);
            }
    }
    if (l15 == 0) {
        #pragma unroll
        for (int M = 0; M < 2; ++M)
            #pragma unroll
            for (int r = 0; r < 4; ++r) {
                int ch = 16 * M + lg * 4 + r;
                sred[wv][ch] = sumv[M][r];
                sred[wv][32 + ch] = sqv[M][r];
            }
    }
    __syncthreads();
    if (tid < 64) {
        float v = sred[0][tid] + sred[1][tid] + sred[2][tid] + sred[3][tid];
        atomicAdd(&stats[tid], v);
    }
}

// ---------------- fast kernel D: fused finalize + normalize + relu ----------------
__global__ __launch_bounds__(256)
void norm_relu_fused_kernel(float* __restrict__ y, const float* __restrict__ stats,
                            const float* __restrict__ gamma, const float* __restrict__ beta)
{
    __shared__ float ssc[32], ssh[32];
    if (threadIdx.x < 32) {
        int c = threadIdx.x;
        const float M = (float)NB * (float)CHW;
        float mean = stats[c] / M;
        float var  = stats[32 + c] / M - mean * mean;
        float sc = gamma[c] * rsqrtf(var + EPS);
        ssc[c] = sc;
        ssh[c] = beta[c] - mean * sc;
    }
    __syncthreads();

    const long long total4 = (long long)NB * DIMS * CHW / 4;
    const int nthreads = gridDim.x * blockDim.x;
    float4* y4 = reinterpret_cast<float4*>(y);
    for (long long i = (long long)blockIdx.x * blockDim.x + threadIdx.x; i < total4; i += nthreads) {
        int c = (int)((i / (CHW / 4)) & 31);
        float sc = ssc[c];
        float sh = ssh[c];
        float4 v = y4[i];
        v.x = fmaxf(fmaf(v.x, sc, sh), 0.f);
        v.y = fmaxf(fmaf(v.y, sc, sh), 0.f);
        v.z = fmaxf(fmaf(v.z, sc, sh), 0.f);
        v.w = fmaxf(fmaf(v.w, sc, sh), 0.f);
        y4[i] = v;
    }
}

// ================= fallback kernels (round-1 fp32 path, unused when ws suffices) =====
__global__ __launch_bounds__(256)
void routing_kernel(const float* __restrict__ std_x, const int* __restrict__ epochs,
                    const float* __restrict__ c1w, const float* __restrict__ c1b,
                    const float* __restrict__ c2w, const float* __restrict__ c2b,
                    const float* __restrict__ fcw, const float* __restrict__ fcb,
                    float* __restrict__ phi_out)
{
    const int b = blockIdx.x;
    const int tid = threadIdx.x;
    __shared__ float sx[32 * 32];
    __shared__ float h1[16 * 28 * 28];
    __shared__ float cmax[32];

    for (int i = tid; i < 1024; i += 256) sx[i] = std_x[b * 1024 + i];
    if (tid < 32) cmax[tid] = 0.f;
    __syncthreads();

    for (int idx = tid; idx < 16 * 28 * 28; idx += 256) {
        int xw = idx % 28;
        int r = idx / 28;
        int xh = r % 28;
        int oc = r / 28;
        float s = c1b[oc];
        #pragma unroll
        for (int ky = 0; ky < 5; ++ky)
            #pragma unroll
            for (int kx = 0; kx < 5; ++kx)
                s = fmaf(sx[(xh + ky) * 32 + xw + kx], c1w[oc * 25 + ky * 5 + kx], s);
        h1[idx] = fmaxf(s, 0.f);
    }
    __syncthreads();

    for (int idx = tid; idx < 32 * 24 * 24; idx += 256) {
        int xw = idx % 24;
        int r = idx / 24;
        int xh = r % 24;
        int oc = r / 24;
        float s = c2b[oc];
        for (int ic = 0; ic < 16; ++ic) {
            const float* hp = &h1[ic * 784];
            const float* wp = &c2w[(oc * 16 + ic) * 25];
            #pragma unroll
            for (int ky = 0; ky < 5; ++ky)
                #pragma unroll
                for (int kx = 0; kx < 5; ++kx)
                    s = fmaf(hp[(xh + ky) * 28 + xw + kx], wp[ky * 5 + kx], s);
        }
        s = fmaxf(s, 0.f);
        atomicMax(reinterpret_cast<int*>(&cmax[oc]), __float_as_int(s));
    }
    __syncthreads();

    if (tid == 0) {
        int ep = epochs[0];
        float tau = (ep < 10) ? (30.0f - 2.9f * (float)ep) : 1.0f;
        float lg[8];
        float mx = -1e30f;
        #pragma unroll
        for (int n = 0; n < 8; ++n) {
            float s = fcb[n];
            #pragma unroll
            for (int k = 0; k < 32; ++k) s = fmaf(cmax[k], fcw[n * 32 + k], s);
            lg[n] = s / tau;
            mx = fmaxf(mx, lg[n]);
        }
        float den = 0.f;
        #pragma unroll
        for (int n = 0; n < 8; ++n) { lg[n] = expf(lg[n] - mx); den += lg[n]; }
        #pragma unroll
        for (int n = 0; n < 8; ++n) phi_out[b * 8 + n] = lg[n] / den;
    }
}

__global__ __launch_bounds__(256)
void dynw_kernel(const float* __restrict__ phi, const float* __restrict__ weights,
                 const float* __restrict__ biases, float* __restrict__ dyn_w,
                 float* __restrict__ dyn_b, float* __restrict__ stats)
{
    const int b = blockIdx.x;
    const int tid = threadIdx.x;
    __shared__ float ph[8];
    if (tid < 8) ph[tid] = phi[b * 8 + tid];
    __syncthreads();

    for (int j = tid; j < DIMS * IN_DIM * 27; j += 256) {
        float s = 0.f;
        #pragma unroll
        for (int n = 0; n < 8; ++n) s = fmaf(ph[n], weights[n * (DIMS * IN_DIM * 27) + j], s);
        dyn_w[b * (DIMS * IN_DIM * 27) + j] = s;
    }
    if (tid < 32) {
        float s = 0.f;
        #pragma unroll
        for (int n = 0; n < 8; ++n) s = fmaf(ph[n], biases[n * 32 + tid], s);
        dyn_b[b * 32 + tid] = s;
    }
    if (b == 0 && tid < 64) stats[tid] = 0.f;
}

__global__ __launch_bounds__(256)
void conv3d_kernel(const float* __restrict__ x, const float* __restrict__ dyn_w,
                   const float* __restrict__ dyn_b, float* __restrict__ y,
                   float* __restrict__ stats)
{
    const int htile = blockIdx.x;
    const int t     = blockIdx.y;
    const int b     = blockIdx.z;
    const int tid   = threadIdx.x;
    const int w     = tid & 127;
    const int hh    = tid >> 7;
    const int h0    = htile * 2;

    __shared__ float tile[3][8][4][114];

    float acc[32];
    #pragma unroll
    for (int c = 0; c < 32; ++c) acc[c] = 0.f;

    const float* wb = dyn_w + b * (DIMS * IN_DIM * 27);
    const float* xb = x + (size_t)b * IN_DIM * CHW;

    for (int ic0 = 0; ic0 < 32; ic0 += 8) {
        __syncthreads();
        for (int idx = tid; idx < 3 * 8 * 4 * 114; idx += 256) {
            int w_ = idx % 114;
            int r  = idx / 114;
            int h_ = r & 3;
            int r2 = r >> 2;
            int i_ = r2 & 7;
            int dt_ = r2 >> 3;
            int gt = t + dt_ - 1;
            int gh = h0 - 1 + h_;
            int gw = w_ - 1;
            float v = 0.f;
            if ((unsigned)gt < (unsigned)TT && (unsigned)gh < (unsigned)HH && (unsigned)gw < (unsigned)WW)
                v = xb[(size_t)((ic0 + i_) * TT + gt) * HW + gh * WW + gw];
            tile[dt_][i_][h_][w_] = v;
        }
        __syncthreads();

        if (w < WW) {
            for (int i = 0; i < 8; ++i) {
                #pragma unroll
                for (int dt = 0; dt < 3; ++dt) {
                    float xv[9];
                    #pragma unroll
                    for (int dh = 0; dh < 3; ++dh)
                        #pragma unroll
                        for (int dw = 0; dw < 3; ++dw)
                            xv[dh * 3 + dw] = tile[dt][i][hh + dh][w + dw];
                    const float* wp = wb + (ic0 + i) * 27 + dt * 9;
                    #pragma unroll
                    for (int c = 0; c < 32; ++c) {
                        const float* wc = wp + c * 864;
                        #pragma unroll
                        for (int k = 0; k < 9; ++k)
                            acc[c] = fmaf(xv[k], wc[k], acc[c]);
                    }
                }
            }
        }
    }

    const float* db = dyn_b + b * 32;
    if (w < WW) {
        #pragma unroll
        for (int c = 0; c < 32; ++c) acc[c] += db[c];
    }

    __shared__ float ssum[32], ssq[32];
    if (tid < 32) { ssum[tid] = 0.f; ssq[tid] = 0.f; }
    __syncthreads();
    #pragma unroll
    for (int c = 0; c < 32; ++c) {
        float s = (w < WW) ? acc[c] : 0.f;
        float q = s * s;
        #pragma unroll
        for (int off = 32; off >= 1; off >>= 1) {
            s += __shfl_down(s, off);
            q += __shfl_down(q, off);
        }
        if ((tid & 63) == 0) { atomicAdd(&ssum[c], s); atomicAdd(&ssq[c], q); }
    }
    __syncthreads();
    if (tid < 32) {
        atomicAdd(&stats[tid], ssum[tid]);
        atomicAdd(&stats[32 + tid], ssq[tid]);
    }

    if (w < WW) {
        size_t base = ((size_t)(b * 32) * TT + t) * HW + (size_t)(h0 + hh) * WW + w;
        #pragma unroll
        for (int c = 0; c < 32; ++c)
            y[base + (size_t)c * CHW] = acc[c];
    }
}

__global__ void stats_finalize_kernel(const float* __restrict__ stats,
                                      const float* __restrict__ gamma,
                                      const float* __restrict__ beta,
                                      float* __restrict__ scaleshift)
{
    int c = threadIdx.x;
    const float M = (float)NB * (float)CHW;
    float mean = stats[c] / M;
    float var  = stats[32 + c] / M - mean * mean;
    float sc = gamma[c] * rsqrtf(var + EPS);
    scaleshift[c] = sc;
    scaleshift[32 + c] = beta[c] - mean * sc;
}

__global__ __launch_bounds__(256)
void norm_relu_kernel(float* __restrict__ y, const float* __restrict__ scaleshift)
{
    const long long total4 = (long long)NB * DIMS * CHW / 4;
    const int nthreads = gridDim.x * blockDim.x;
    float4* y4 = reinterpret_cast<float4*>(y);
    for (long long i = (long long)blockIdx.x * blockDim.x + threadIdx.x; i < total4; i += nthreads) {
        int c = (int)((i / (CHW / 4)) & 31);
        float sc = scaleshift[c];
        float sh = scaleshift[32 + c];
        float4 v = y4[i];
        v.x = fmaxf(fmaf(v.x, sc, sh), 0.f);
        v.y = fmaxf(fmaf(v.y, sc, sh), 0.f);
        v.z = fmaxf(fmaf(v.z, sc, sh), 0.f);
        v.w = fmaxf(fmaf(v.w, sc, sh), 0.f);
        y4[i] = v;
    }
}

extern "C" void kernel_launch(void* const* d_in, const int* in_sizes, int n_in,
                              void* d_out, int out_size, void* d_ws, size_t ws_size,
                              hipStream_t stream)
{
    const float* x      = (const float*)d_in[0];
    const float* std_x  = (const float*)d_in[1];
    const int*   epochs = (const int*)d_in[2];
    const float* weights= (const float*)d_in[3];
    const float* biases = (const float*)d_in[4];
    const float* c1w    = (const float*)d_in[5];
    const float* c1b    = (const float*)d_in[6];
    const float* c2w    = (const float*)d_in[7];
    const float* c2b    = (const float*)d_in[8];
    const float* fcw    = (const float*)d_in[9];
    const float* fcb    = (const float*)d_in[10];
    const float* gamma  = (const float*)d_in[11];
    const float* beta   = (const float*)d_in[12];

    float* out = (float*)d_out;
    float* ws  = (float*)d_ws;

    if (ws_size >= WS_NEED_BYTES) {
        // ---------------- fast bf16-MFMA path ----------------
        float* phi   = ws + WSF_PHI;
        float* dyn_b = ws + WSF_DYNB;
        float* stats = ws + WSF_STATS;
        float* zerob = ws + WSF_ZERO;
        unsigned short* dwb = (unsigned short*)(ws + WSF_HDR_FLOATS);
        unsigned short* xT  = dwb + (size_t)NB * 27 * 1024;
        // routing scratch aliased into xT region (consumed before xpose overwrites)
        float* h1g  = (float*)xT;
        float* cmax = h1g + NB * 16 * 784;

        routing_conv1_kernel<<<dim3(16, NB), 256, 0, stream>>>(std_x, c1w, c1b, h1g);
        routing_conv2max_kernel<<<dim3(32, NB), 256, 0, stream>>>(h1g, c2w, c2b, cmax);
        routing_fc_kernel<<<1, 64, 0, stream>>>(cmax, epochs, fcw, fcb, phi);
        dynwb_kernel<<<dim3(32, NB), 256, 0, stream>>>(phi, weights, biases, dwb, dyn_b, stats);
        xpose_kernel<<<dim3(HH, TT, NB), 256, 0, stream>>>(x, xT);
        convmf_kernel<<<dim3(49, 8, NB), 256, 0, stream>>>(xT, dwb, dyn_b, zerob, out, stats);
        norm_relu_fused_kernel<<<2048, 256, 0, stream>>>(out, stats, gamma, beta);
    } else {
        // ---------------- fallback fp32 path ----------------
        float* phi   = ws + WS_PHI;
        float* dyn_w = ws + WS_DYNW;
        float* dyn_b = ws + WS_DYNB;
        float* stats = ws + WS_STATS;
        float* ss    = ws + WS_SS;

        routing_kernel<<<NB, 256, 0, stream>>>(std_x, epochs, c1w, c1b, c2w, c2b, fcw, fcb, phi);
        dynw_kernel<<<NB, 256, 0, stream>>>(phi, weights, biases, dyn_w, dyn_b, stats);
        conv3d_kernel<<<dim3(HH / 2, TT, NB), 256, 0, stream>>>(x, dyn_w, dyn_b, out, stats);
        stats_finalize_kernel<<<1, 32, 0, stream>>>(stats, gamma, beta, ss);
        norm_relu_kernel<<<2048, 256, 0, stream>>>(out, ss);
    }
}

// Round 5
// 571.018 us; speedup vs baseline: 9.0079x; 1.1105x over previous
//
#include <hip/hip_runtime.h>
#include <hip/hip_bf16.h>

#define IN_DIM 32
#define DIMS   32
#define NW     8
#define NB     8
#define TT     16
#define HH     112
#define WW     112
#define HW     (HH*WW)           // 12544
#define CHW    (TT*HW)           // 200704
#define EPS    1e-5f

typedef __attribute__((ext_vector_type(8))) short bf16x8;
typedef __attribute__((ext_vector_type(4))) float f32x4;

static __device__ __forceinline__ unsigned short f2bf(float f) {
    unsigned u = __float_as_uint(f);
    unsigned r = u + 0x7FFFu + ((u >> 16) & 1u);
    return (unsigned short)(r >> 16);
}

static __device__ __forceinline__ void gload_lds16(const void* gptr, void* lptr) {
    __builtin_amdgcn_global_load_lds(
        (const __attribute__((address_space(1))) unsigned int*)gptr,
        (__attribute__((address_space(3))) unsigned int*)lptr,
        16, 0, 0);
}

// ======================= fast-path ws layout (IDENTICAL footprint) =======
// floats:   phi[64] | dyn_b[256] | stats[64] | zerobuf[64]   (448 floats)
// then:     dwb  bf16 [8][27][32oc][32ic]  = 221184 ushorts
// then:     xT   bf16 [8][16][112][112][32] = 51380224 ushorts
#define WSF_PHI    0
#define WSF_DYNB   64
#define WSF_STATS  320
#define WSF_ZERO   384
#define WSF_HDR_FLOATS 448
#define XT_USHORTS  ((size_t)NB*CHW*32)
#define WS_NEED_BYTES (WSF_HDR_FLOATS*4 + (size_t)NB*27*1024*2 + XT_USHORTS*2)

// ======================= fallback ws layout (round-1) ==============
#define WS_PHI    0
#define WS_DYNW   64
#define WS_DYNB   221248
#define WS_STATS  221504
#define WS_SS     221568

// ---------------- fast routing 1: conv1 5x5 VALID 1->16 + relu ----------------
__global__ __launch_bounds__(256)
void routing_conv1_kernel(const float* __restrict__ std_x,
                          const float* __restrict__ c1w, const float* __restrict__ c1b,
                          float* __restrict__ h1g)
{
    const int oc = blockIdx.x, b = blockIdx.y;
    const int tid = threadIdx.x;
    __shared__ float sx[1024];
    for (int i = tid; i < 1024; i += 256) sx[i] = std_x[b * 1024 + i];
    __syncthreads();

    float wloc[25];
    #pragma unroll
    for (int k = 0; k < 25; ++k) wloc[k] = c1w[oc * 25 + k];
    const float bias = c1b[oc];

    for (int idx = tid; idx < 784; idx += 256) {
        int xw = idx % 28, xh = idx / 28;
        float s = bias;
        #pragma unroll
        for (int ky = 0; ky < 5; ++ky)
            #pragma unroll
            for (int kx = 0; kx < 5; ++kx)
                s = fmaf(sx[(xh + ky) * 32 + xw + kx], wloc[ky * 5 + kx], s);
        h1g[(b * 16 + oc) * 784 + idx] = fmaxf(s, 0.f);
    }
}

// ---------------- fast routing 2: conv2 5x5 VALID 16->32 + relu + spatial max ----
__global__ __launch_bounds__(256)
void routing_conv2max_kernel(const float* __restrict__ h1g,
                             const float* __restrict__ c2w, const float* __restrict__ c2b,
                             float* __restrict__ cmax)
{
    const int oc = blockIdx.x, b = blockIdx.y;
    const int tid = threadIdx.x;
    __shared__ float h1s[16 * 784];   // 50176 B
    __shared__ float wred[4];

    for (int i = tid; i < 16 * 784; i += 256) h1s[i] = h1g[b * (16 * 784) + i];
    __syncthreads();

    float m = 0.f;
    for (int idx = tid; idx < 576; idx += 256) {
        int xw = idx % 24, xh = idx / 24;
        float s = c2b[oc];
        for (int ic = 0; ic < 16; ++ic) {
            const float* hp = &h1s[ic * 784];
            const float* wp = &c2w[(oc * 16 + ic) * 25];
            #pragma unroll
            for (int ky = 0; ky < 5; ++ky)
                #pragma unroll
                for (int kx = 0; kx < 5; ++kx)
                    s = fmaf(hp[(xh + ky) * 28 + xw + kx], wp[ky * 5 + kx], s);
        }
        m = fmaxf(m, s);
    }
    #pragma unroll
    for (int off = 32; off >= 1; off >>= 1) m = fmaxf(m, __shfl_down(m, off));
    if ((tid & 63) == 0) wred[tid >> 6] = m;
    __syncthreads();
    if (tid == 0) {
        float r = fmaxf(fmaxf(wred[0], wred[1]), fmaxf(wred[2], wred[3]));
        cmax[b * 32 + oc] = r;
    }
}

// ---------------- fast routing 3: fc + softmax -> phi ----------------
__global__ __launch_bounds__(64)
void routing_fc_kernel(const float* __restrict__ cmax, const int* __restrict__ epochs,
                       const float* __restrict__ fcw, const float* __restrict__ fcb,
                       float* __restrict__ phi_out)
{
    const int tid = threadIdx.x;
    const int b = tid >> 3, n = tid & 7;
    int ep = epochs[0];
    float tau = (ep < 10) ? (30.0f - 2.9f * (float)ep) : 1.0f;
    float s = fcb[n];
    #pragma unroll
    for (int k = 0; k < 32; ++k) s = fmaf(cmax[b * 32 + k], fcw[n * 32 + k], s);
    s /= tau;
    float mx = s;
    #pragma unroll
    for (int off = 1; off < 8; off <<= 1) mx = fmaxf(mx, __shfl_xor(mx, off, 8));
    float e = expf(s - mx);
    float den = e;
    #pragma unroll
    for (int off = 1; off < 8; off <<= 1) den += __shfl_xor(den, off, 8);
    phi_out[b * 8 + n] = e / den;
}

// ---------------- fast kernel A: x (NCDHW f32) -> xT (NDHWC bf16) ----------------
#define XS 232   // LDS row stride bytes per ic (multiple of 8)
__global__ __launch_bounds__(256)
void xpose_kernel(const float* __restrict__ x, unsigned short* __restrict__ xT)
{
    const int h = blockIdx.x, t = blockIdx.y, b = blockIdx.z;
    const int tid = threadIdx.x;
    __shared__ __align__(16) unsigned char lds[32 * XS];

    for (int idx = tid; idx < 32 * 28; idx += 256) {
        int ic = idx / 28;
        int w4 = idx - ic * 28;
        const float4 v = *(const float4*)(x + (((size_t)(b * 32 + ic) * TT + t) * HW) + h * 112 + w4 * 4);
        uint2 pk;
        pk.x = (unsigned)f2bf(v.x) | ((unsigned)f2bf(v.y) << 16);
        pk.y = (unsigned)f2bf(v.z) | ((unsigned)f2bf(v.w) << 16);
        *(uint2*)(lds + ic * XS + w4 * 8) = pk;
    }
    __syncthreads();

    unsigned short* op = xT + ((((size_t)b * TT + t) * HH + h) * WW) * 32;
    for (int idx = tid; idx < 448; idx += 256) {   // 112 w * 4 icg
        int w = idx >> 2, icg = idx & 3;
        unsigned int pk[4];
        #pragma unroll
        for (int j = 0; j < 4; ++j) {
            unsigned short lo = *(unsigned short*)(lds + (icg * 8 + 2 * j) * XS + w * 2);
            unsigned short hi = *(unsigned short*)(lds + (icg * 8 + 2 * j + 1) * XS + w * 2);
            pk[j] = (unsigned int)lo | ((unsigned int)hi << 16);
        }
        uint4 v; v.x = pk[0]; v.y = pk[1]; v.z = pk[2]; v.w = pk[3];
        *(uint4*)(op + (size_t)w * 32 + icg * 8) = v;
    }
}

// ---------------- fast kernel B: dyn weights (coalesced) -> bf16 [b][tap][oc][ic] ----
__global__ __launch_bounds__(256)
void dynwb_kernel(const float* __restrict__ phi, const float* __restrict__ weights,
                  const float* __restrict__ biases, unsigned short* __restrict__ dwb,
                  float* __restrict__ dyn_b, float* __restrict__ statszero)
{
    const int oc = blockIdx.x;   // 0..31
    const int b  = blockIdx.y;   // 0..7
    const int tid = threadIdx.x;
    __shared__ float ph[8];
    if (tid < 8) ph[tid] = phi[b * 8 + tid];
    __syncthreads();

    for (int i = tid; i < 864; i += 256) {
        float s = 0.f;
        #pragma unroll
        for (int n = 0; n < 8; ++n)
            s = fmaf(ph[n], weights[(size_t)(n * 32 + oc) * 864 + i], s);
        int ic = i / 27;
        int tap = i - 27 * ic;
        dwb[((size_t)(b * 27 + tap) << 10) + (oc << 5) + ic] = f2bf(s);
    }
    if (tid == 0) {
        float s = 0.f;
        #pragma unroll
        for (int n = 0; n < 8; ++n) s = fmaf(ph[n], biases[n * 32 + oc], s);
        dyn_b[b * 32 + oc] = s;
    }
    if (oc == 0 && b == 0 && tid < 128) statszero[tid] = 0.f;
}

// ---------------- fast kernel C: MFMA conv3d, weights-in-LDS + reg-staged x ----------
// block: 256 thr (4 waves) -> (b, tpair, 16h x 16w), all 32 oc, 2 t outputs
// LDS: weights 55296 B (27 taps x 32 oc x 32 ic, icg swizzled) +
//      x-plane 20736 B (18x18 px x 32 ic, icg swizzled) + sred 1024 B = 77056 B
#define XROWSTRIDE   1152            // 18 px * 64 B
#define XLDS_BYTES   20736           // 1296 cells * 16
#define WLDS_BYTES   55296           // 3456 cells * 16
#define PLANE_BYTES_G 802816ull      // t-plane stride in xT (bytes) = 112*112*64
__global__ __launch_bounds__(256, 2)
void convmf_kernel(const unsigned short* __restrict__ xT, const unsigned short* __restrict__ dwb,
                   const float* __restrict__ dyn_b, float* __restrict__ y,
                   float* __restrict__ stats)
{
    const int hblk = blockIdx.x / 7, wblk = blockIdx.x % 7;
    const int tpair = blockIdx.y, b = blockIdx.z;
    const int h0 = hblk * 16, w0 = wblk * 16, t0 = tpair * 2;
    const int tid = threadIdx.x;
    const int lane = tid & 63, wv = tid >> 6;
    const int l15 = lane & 15, lg = lane >> 4;

    __shared__ __align__(16) unsigned char wlds[WLDS_BYTES];
    __shared__ __align__(16) unsigned char xlds[XLDS_BYTES];
    __shared__ float sred[4][64];

    // ---- stage ALL weights for this b into LDS (source pre-swizzled, dest linear) ----
    {
        const unsigned short* wb = dwb + (size_t)b * 27 * 1024;
        unsigned char* ldsw = wlds + (size_t)(tid & ~63) * 16;
        #pragma unroll
        for (int k = 0; k < 14; ++k) {
            if (k < 13 || tid < 128) {           // 3456 cells = 13.5 * 256
                int cid = k * 256 + tid;
                int tap = cid >> 7;
                int rem = cid & 127;
                int oc  = rem >> 2;
                int icg_s = rem & 3;
                int icg_l = icg_s ^ ((oc >> 1) & 3);
                gload_lds16(wb + tap * 1024 + oc * 32 + icg_l * 8, ldsw + k * 4096);
            }
        }
    }

    // ---- per-thread x staging cell precompute (6 cells/thread, logical order) ----
    const unsigned char* xbase = (const unsigned char*)xT + (size_t)b * TT * PLANE_BYTES_G;
    int srcoff[6], dsto[6];
    bool okj[6], valid[6];
    #pragma unroll
    for (int j = 0; j < 6; ++j) {
        int cid = j * 256 + tid;
        int hr = cid / 72, rem = cid - hr * 72;
        int p = rem >> 2, icg = rem & 3;
        int gh = h0 - 1 + hr, gw = w0 - 1 + p;
        valid[j] = (cid < 1296);
        okj[j] = valid[j] && ((unsigned)gh < (unsigned)HH) && ((unsigned)gw < (unsigned)WW);
        srcoff[j] = (gh * WW + gw) * 64 + icg * 16;
        dsto[j] = (hr * 72 + p * 4 + (icg ^ ((p >> 1) & 3))) * 16;
    }
    uint4 xs[6];

#define LOADX(TX) do {                                                        \
        const int tx_ = (TX);                                                 \
        const bool tok_ = ((unsigned)tx_ < (unsigned)TT);                     \
        const unsigned char* pb_ = xbase + (size_t)tx_ * PLANE_BYTES_G;       \
        _Pragma("unroll")                                                     \
        for (int j = 0; j < 6; ++j) {                                         \
            uint4 v_; v_.x = 0; v_.y = 0; v_.z = 0; v_.w = 0;                 \
            if (tok_ && okj[j]) v_ = *(const uint4*)(pb_ + srcoff[j]);        \
            xs[j] = v_;                                                       \
        }                                                                     \
    } while (0)

#define WRITEX() do {                                                         \
        _Pragma("unroll")                                                     \
        for (int j = 0; j < 6; ++j)                                           \
            if (valid[j]) *(uint4*)(xlds + dsto[j]) = xs[j];                  \
    } while (0)

    // swizzled read offsets
    const int wsw = l15 * 64 + ((lg ^ ((l15 >> 1) & 3)) * 16);
    int xoff[3];
    #pragma unroll
    for (int dw = 0; dw < 3; ++dw) {
        int px = l15 + dw;
        xoff[dw] = px * 64 + ((lg ^ ((px >> 1) & 3)) * 16);
    }

    f32x4 acc0[4][2], acc1[4][2];
    #pragma unroll
    for (int g = 0; g < 4; ++g)
        #pragma unroll
        for (int M = 0; M < 2; ++M) { acc0[g][M] = (f32x4)0.f; acc1[g][M] = (f32x4)0.f; }

    // prologue: load plane t0-1 to regs; wait (also drains weight gload_lds); write; barrier
    LOADX(t0 - 1);
    asm volatile("s_waitcnt vmcnt(0)" ::: "memory");
    WRITEX();
    __syncthreads();

    #pragma unroll
    for (int tp = 0; tp < 4; ++tp) {
        if (tp < 3) LOADX(t0 + tp);     // prefetch next plane under compute

        const bool do0 = (tp <= 2), do1 = (tp >= 1);
        #pragma unroll
        for (int dhw = 0; dhw < 9; ++dhw) {
            const int dh = dhw / 3, dw = dhw - dh * 3;
            bf16x8 a00, a01, a10, a11;
            if (do0) {
                const int off = (tp * 9 + dhw) * 2048 + wsw;
                a00 = *(const bf16x8*)(wlds + off);
                a01 = *(const bf16x8*)(wlds + off + 1024);
            }
            if (do1) {
                const int off = ((tp - 1) * 9 + dhw) * 2048 + wsw;
                a10 = *(const bf16x8*)(wlds + off);
                a11 = *(const bf16x8*)(wlds + off + 1024);
            }
            const int rb = wv * 4 + dh;
            #pragma unroll
            for (int g = 0; g < 4; ++g) {
                bf16x8 bb = *(const bf16x8*)(xlds + (rb + g) * XROWSTRIDE + xoff[dw]);
                if (do0) {
                    acc0[g][0] = __builtin_amdgcn_mfma_f32_16x16x32_bf16(a00, bb, acc0[g][0], 0, 0, 0);
                    acc0[g][1] = __builtin_amdgcn_mfma_f32_16x16x32_bf16(a01, bb, acc0[g][1], 0, 0, 0);
                }
                if (do1) {
                    acc1[g][0] = __builtin_amdgcn_mfma_f32_16x16x32_bf16(a10, bb, acc1[g][0], 0, 0, 0);
                    acc1[g][1] = __builtin_amdgcn_mfma_f32_16x16x32_bf16(a11, bb, acc1[g][1], 0, 0, 0);
                }
            }
        }

        if (tp < 3) {
            __syncthreads();                                   // all waves done reading xlds
            asm volatile("s_waitcnt vmcnt(0)" ::: "memory");   // xs arrived (hidden under compute)
            WRITEX();
            __syncthreads();                                   // writes visible
        }
    }
#undef LOADX
#undef WRITEX

    // ---- epilogue: bias, stats, store ----
    f32x4 bias[2];
    #pragma unroll
    for (int M = 0; M < 2; ++M)
        #pragma unroll
        for (int r = 0; r < 4; ++r)
            bias[M][r] = dyn_b[b * 32 + 16 * M + lg * 4 + r];

    float sumv[2][4], sqv[2][4];
    #pragma unroll
    for (int M = 0; M < 2; ++M)
        #pragma unroll
        for (int r = 0; r < 4; ++r) { sumv[M][r] = 0.f; sqv[M][r] = 0.f; }

    #pragma unroll
    for (int g = 0; g < 4; ++g) {
        const int h = h0 + wv * 4 + g;
        #pragma unroll
        for (int M = 0; M < 2; ++M) {
            f32x4 v0 = acc0[g][M] + bias[M];
            f32x4 v1 = acc1[g][M] + bias[M];
            const int oc0 = 16 * M + lg * 4;
            size_t base = (((size_t)(b * 32 + oc0) * TT + t0) * HW) + h * 112 + w0 + l15;
            #pragma unroll
            for (int r = 0; r < 4; ++r) {
                sumv[M][r] += v0[r] + v1[r];
                sqv[M][r]  += v0[r] * v0[r] + v1[r] * v1[r];
                y[base + (size_t)r * TT * HW] = v0[r];
                y[base + (size_t)r * TT * HW + HW] = v1[r];
            }
        }
    }

    #pragma unroll
    for (int off = 1; off < 16; off <<= 1) {
        #pragma unroll
        for (int M = 0; M < 2; ++M)
            #pragma unroll
            for (int r = 0; r < 4; ++r) {
                sumv[M][r] += __shfl_xor(sumv[M][r], off);
                sqv[M][r]  += __shfl_xor(sqv[M][r], off);
            }
    }
    if (l15 == 0) {
        #pragma unroll
        for (int M = 0; M < 2; ++M)
            #pragma unroll
            for (int r = 0; r < 4; ++r) {
                int ch = 16 * M + lg * 4 + r;
                sred[wv][ch] = sumv[M][r];
                sred[wv][32 + ch] = sqv[M][r];
            }
    }
    __syncthreads();
    if (tid < 64) {
        float v = sred[0][tid] + sred[1][tid] + sred[2][tid] + sred[3][tid];
        atomicAdd(&stats[tid], v);
    }
}

// ---------------- fast kernel D: fused finalize + normalize + relu ----------------
__global__ __launch_bounds__(256)
void norm_relu_fused_kernel(float* __restrict__ y, const float* __restrict__ stats,
                            const float* __restrict__ gamma, const float* __restrict__ beta)
{
    __shared__ float ssc[32], ssh[32];
    if (threadIdx.x < 32) {
        int c = threadIdx.x;
        const float M = (float)NB * (float)CHW;
        float mean = stats[c] / M;
        float var  = stats[32 + c] / M - mean * mean;
        float sc = gamma[c] * rsqrtf(var + EPS);
        ssc[c] = sc;
        ssh[c] = beta[c] - mean * sc;
    }
    __syncthreads();

    const long long total4 = (long long)NB * DIMS * CHW / 4;
    const int nthreads = gridDim.x * blockDim.x;
    float4* y4 = reinterpret_cast<float4*>(y);
    for (long long i = (long long)blockIdx.x * blockDim.x + threadIdx.x; i < total4; i += nthreads) {
        int c = (int)((i / (CHW / 4)) & 31);
        float sc = ssc[c];
        float sh = ssh[c];
        float4 v = y4[i];
        v.x = fmaxf(fmaf(v.x, sc, sh), 0.f);
        v.y = fmaxf(fmaf(v.y, sc, sh), 0.f);
        v.z = fmaxf(fmaf(v.z, sc, sh), 0.f);
        v.w = fmaxf(fmaf(v.w, sc, sh), 0.f);
        y4[i] = v;
    }
}

// ================= fallback kernels (round-1 fp32 path, unused when ws suffices) =====
__global__ __launch_bounds__(256)
void routing_kernel(const float* __restrict__ std_x, const int* __restrict__ epochs,
                    const float* __restrict__ c1w, const float* __restrict__ c1b,
                    const float* __restrict__ c2w, const float* __restrict__ c2b,
                    const float* __restrict__ fcw, const float* __restrict__ fcb,
                    float* __restrict__ phi_out)
{
    const int b = blockIdx.x;
    const int tid = threadIdx.x;
    __shared__ float sx[32 * 32];
    __shared__ float h1[16 * 28 * 28];
    __shared__ float cmax[32];

    for (int i = tid; i < 1024; i += 256) sx[i] = std_x[b * 1024 + i];
    if (tid < 32) cmax[tid] = 0.f;
    __syncthreads();

    for (int idx = tid; idx < 16 * 28 * 28; idx += 256) {
        int xw = idx % 28;
        int r = idx / 28;
        int xh = r % 28;
        int oc = r / 28;
        float s = c1b[oc];
        #pragma unroll
        for (int ky = 0; ky < 5; ++ky)
            #pragma unroll
            for (int kx = 0; kx < 5; ++kx)
                s = fmaf(sx[(xh + ky) * 32 + xw + kx], c1w[oc * 25 + ky * 5 + kx], s);
        h1[idx] = fmaxf(s, 0.f);
    }
    __syncthreads();

    for (int idx = tid; idx < 32 * 24 * 24; idx += 256) {
        int xw = idx % 24;
        int r = idx / 24;
        int xh = r % 24;
        int oc = r / 24;
        float s = c2b[oc];
        for (int ic = 0; ic < 16; ++ic) {
            const float* hp = &h1[ic * 784];
            const float* wp = &c2w[(oc * 16 + ic) * 25];
            #pragma unroll
            for (int ky = 0; ky < 5; ++ky)
                #pragma unroll
                for (int kx = 0; kx < 5; ++kx)
                    s = fmaf(hp[(xh + ky) * 28 + xw + kx], wp[ky * 5 + kx], s);
        }
        s = fmaxf(s, 0.f);
        atomicMax(reinterpret_cast<int*>(&cmax[oc]), __float_as_int(s));
    }
    __syncthreads();

    if (tid == 0) {
        int ep = epochs[0];
        float tau = (ep < 10) ? (30.0f - 2.9f * (float)ep) : 1.0f;
        float lg[8];
        float mx = -1e30f;
        #pragma unroll
        for (int n = 0; n < 8; ++n) {
            float s = fcb[n];
            #pragma unroll
            for (int k = 0; k < 32; ++k) s = fmaf(cmax[k], fcw[n * 32 + k], s);
            lg[n] = s / tau;
            mx = fmaxf(mx, lg[n]);
        }
        float den = 0.f;
        #pragma unroll
        for (int n = 0; n < 8; ++n) { lg[n] = expf(lg[n] - mx); den += lg[n]; }
        #pragma unroll
        for (int n = 0; n < 8; ++n) phi_out[b * 8 + n] = lg[n] / den;
    }
}

__global__ __launch_bounds__(256)
void dynw_kernel(const float* __restrict__ phi, const float* __restrict__ weights,
                 const float* __restrict__ biases, float* __restrict__ dyn_w,
                 float* __restrict__ dyn_b, float* __restrict__ stats)
{
    const int b = blockIdx.x;
    const int tid = threadIdx.x;
    __shared__ float ph[8];
    if (tid < 8) ph[tid] = phi[b * 8 + tid];
    __syncthreads();

    for (int j = tid; j < DIMS * IN_DIM * 27; j += 256) {
        float s = 0.f;
        #pragma unroll
        for (int n = 0; n < 8; ++n) s = fmaf(ph[n], weights[n * (DIMS * IN_DIM * 27) + j], s);
        dyn_w[b * (DIMS * IN_DIM * 27) + j] = s;
    }
    if (tid < 32) {
        float s = 0.f;
        #pragma unroll
        for (int n = 0; n < 8; ++n) s = fmaf(ph[n], biases[n * 32 + tid], s);
        dyn_b[b * 32 + tid] = s;
    }
    if (b == 0 && tid < 64) stats[tid] = 0.f;
}

__global__ __launch_bounds__(256)
void conv3d_kernel(const float* __restrict__ x, const float* __restrict__ dyn_w,
                   const float* __restrict__ dyn_b, float* __restrict__ y,
                   float* __restrict__ stats)
{
    const int htile = blockIdx.x;
    const int t     = blockIdx.y;
    const int b     = blockIdx.z;
    const int tid   = threadIdx.x;
    const int w     = tid & 127;
    const int hh    = tid >> 7;
    const int h0    = htile * 2;

    __shared__ float tile[3][8][4][114];

    float acc[32];
    #pragma unroll
    for (int c = 0; c < 32; ++c) acc[c] = 0.f;

    const float* wb = dyn_w + b * (DIMS * IN_DIM * 27);
    const float* xb = x + (size_t)b * IN_DIM * CHW;

    for (int ic0 = 0; ic0 < 32; ic0 += 8) {
        __syncthreads();
        for (int idx = tid; idx < 3 * 8 * 4 * 114; idx += 256) {
            int w_ = idx % 114;
            int r  = idx / 114;
            int h_ = r & 3;
            int r2 = r >> 2;
            int i_ = r2 & 7;
            int dt_ = r2 >> 3;
            int gt = t + dt_ - 1;
            int gh = h0 - 1 + h_;
            int gw = w_ - 1;
            float v = 0.f;
            if ((unsigned)gt < (unsigned)TT && (unsigned)gh < (unsigned)HH && (unsigned)gw < (unsigned)WW)
                v = xb[(size_t)((ic0 + i_) * TT + gt) * HW + gh * WW + gw];
            tile[dt_][i_][h_][w_] = v;
        }
        __syncthreads();

        if (w < WW) {
            for (int i = 0; i < 8; ++i) {
                #pragma unroll
                for (int dt = 0; dt < 3; ++dt) {
                    float xv[9];
                    #pragma unroll
                    for (int dh = 0; dh < 3; ++dh)
                        #pragma unroll
                        for (int dw = 0; dw < 3; ++dw)
                            xv[dh * 3 + dw] = tile[dt][i][hh + dh][w + dw];
                    const float* wp = wb + (ic0 + i) * 27 + dt * 9;
                    #pragma unroll
                    for (int c = 0; c < 32; ++c) {
                        const float* wc = wp + c * 864;
                        #pragma unroll
                        for (int k = 0; k < 9; ++k)
                            acc[c] = fmaf(xv[k], wc[k], acc[c]);
                    }
                }
            }
        }
    }

    const float* db = dyn_b + b * 32;
    if (w < WW) {
        #pragma unroll
        for (int c = 0; c < 32; ++c) acc[c] += db[c];
    }

    __shared__ float ssum[32], ssq[32];
    if (tid < 32) { ssum[tid] = 0.f; ssq[tid] = 0.f; }
    __syncthreads();
    #pragma unroll
    for (int c = 0; c < 32; ++c) {
        float s = (w < WW) ? acc[c] : 0.f;
        float q = s * s;
        #pragma unroll
        for (int off = 32; off >= 1; off >>= 1) {
            s += __shfl_down(s, off);
            q += __shfl_down(q, off);
        }
        if ((tid & 63) == 0) { atomicAdd(&ssum[c], s); atomicAdd(&ssq[c], q); }
    }
    __syncthreads();
    if (tid < 32) {
        atomicAdd(&stats[tid], ssum[tid]);
        atomicAdd(&stats[32 + tid], ssq[tid]);
    }

    if (w < WW) {
        size_t base = ((size_t)(b * 32) * TT + t) * HW + (size_t)(h0 + hh) * WW + w;
        #pragma unroll
        for (int c = 0; c < 32; ++c)
            y[base + (size_t)c * CHW] = acc[c];
    }
}

__global__ void stats_finalize_kernel(const float* __restrict__ stats,
                                      const float* __restrict__ gamma,
                                      const float* __restrict__ beta,
                                      float* __restrict__ scaleshift)
{
    int c = threadIdx.x;
    const float M = (float)NB * (float)CHW;
    float mean = stats[c] / M;
    float var  = stats[32 + c] / M - mean * mean;
    float sc = gamma[c] * rsqrtf(var + EPS);
    scaleshift[c] = sc;
    scaleshift[32 + c] = beta[c] - mean * sc;
}

__global__ __launch_bounds__(256)
void norm_relu_kernel(float* __restrict__ y, const float* __restrict__ scaleshift)
{
    const long long total4 = (long long)NB * DIMS * CHW / 4;
    const int nthreads = gridDim.x * blockDim.x;
    float4* y4 = reinterpret_cast<float4*>(y);
    for (long long i = (long long)blockIdx.x * blockDim.x + threadIdx.x; i < total4; i += nthreads) {
        int c = (int)((i / (CHW / 4)) & 31);
        float sc = scaleshift[c];
        float sh = scaleshift[32 + c];
        float4 v = y4[i];
        v.x = fmaxf(fmaf(v.x, sc, sh), 0.f);
        v.y = fmaxf(fmaf(v.y, sc, sh), 0.f);
        v.z = fmaxf(fmaf(v.z, sc, sh), 0.f);
        v.w = fmaxf(fmaf(v.w, sc, sh), 0.f);
        y4[i] = v;
    }
}

extern "C" void kernel_launch(void* const* d_in, const int* in_sizes, int n_in,
                              void* d_out, int out_size, void* d_ws, size_t ws_size,
                              hipStream_t stream)
{
    const float* x      = (const float*)d_in[0];
    const float* std_x  = (const float*)d_in[1];
    const int*   epochs = (const int*)d_in[2];
    const float* weights= (const float*)d_in[3];
    const float* biases = (const float*)d_in[4];
    const float* c1w    = (const float*)d_in[5];
    const float* c1b    = (const float*)d_in[6];
    const float* c2w    = (const float*)d_in[7];
    const float* c2b    = (const float*)d_in[8];
    const float* fcw    = (const float*)d_in[9];
    const float* fcb    = (const float*)d_in[10];
    const float* gamma  = (const float*)d_in[11];
    const float* beta   = (const float*)d_in[12];

    float* out = (float*)d_out;
    float* ws  = (float*)d_ws;

    if (ws_size >= WS_NEED_BYTES) {
        // ---------------- fast bf16-MFMA path ----------------
        float* phi   = ws + WSF_PHI;
        float* dyn_b = ws + WSF_DYNB;
        float* stats = ws + WSF_STATS;
        unsigned short* dwb = (unsigned short*)(ws + WSF_HDR_FLOATS);
        unsigned short* xT  = dwb + (size_t)NB * 27 * 1024;
        // routing scratch aliased into xT region (consumed before xpose overwrites)
        float* h1g  = (float*)xT;
        float* cmax = h1g + NB * 16 * 784;

        routing_conv1_kernel<<<dim3(16, NB), 256, 0, stream>>>(std_x, c1w, c1b, h1g);
        routing_conv2max_kernel<<<dim3(32, NB), 256, 0, stream>>>(h1g, c2w, c2b, cmax);
        routing_fc_kernel<<<1, 64, 0, stream>>>(cmax, epochs, fcw, fcb, phi);
        dynwb_kernel<<<dim3(32, NB), 256, 0, stream>>>(phi, weights, biases, dwb, dyn_b, stats);
        xpose_kernel<<<dim3(HH, TT, NB), 256, 0, stream>>>(x, xT);
        convmf_kernel<<<dim3(49, 8, NB), 256, 0, stream>>>(xT, dwb, dyn_b, out, stats);
        norm_relu_fused_kernel<<<2048, 256, 0, stream>>>(out, stats, gamma, beta);
    } else {
        // ---------------- fallback fp32 path ----------------
        float* phi   = ws + WS_PHI;
        float* dyn_w = ws + WS_DYNW;
        float* dyn_b = ws + WS_DYNB;
        float* stats = ws + WS_STATS;
        float* ss    = ws + WS_SS;

        routing_kernel<<<NB, 256, 0, stream>>>(std_x, epochs, c1w, c1b, c2w, c2b, fcw, fcb, phi);
        dynw_kernel<<<NB, 256, 0, stream>>>(phi, weights, biases, dyn_w, dyn_b, stats);
        conv3d_kernel<<<dim3(HH / 2, TT, NB), 256, 0, stream>>>(x, dyn_w, dyn_b, out, stats);
        stats_finalize_kernel<<<1, 32, 0, stream>>>(stats, gamma, beta, ss);
        norm_relu_kernel<<<2048, 256, 0, stream>>>(out, ss);
    }
}